// Round 13
// baseline (705.726 us; speedup 1.0000x reference)
//
#include <hip/hip_runtime.h>
#include <hip/hip_bf16.h>
#include <math.h>

#define HW 9216
#define IMG 96

typedef __bf16 bf16x8 __attribute__((ext_vector_type(8)));
typedef float  f32x4  __attribute__((ext_vector_type(4)));
typedef float  f32x16 __attribute__((ext_vector_type(16)));

__device__ __forceinline__ void gload16(const void* g, void* l) {
    __builtin_amdgcn_global_load_lds((const unsigned int*)g, (unsigned int*)l, 16, 0, 0);
}

#define WAITVN(N) asm volatile("s_waitcnt vmcnt(" #N ")" ::: "memory")
#define BARX()    { asm volatile("" ::: "memory"); __builtin_amdgcn_s_barrier(); asm volatile("" ::: "memory"); }

// ---------------------------------------------------------------------------
// NCHW fp32 -> NHWC bf16 transpose/convert. grid (HW/64, cin/32, N)
// ---------------------------------------------------------------------------
__global__ __launch_bounds__(256) void nchw2nhwc_kernel(
    const float* __restrict__ src, long n_stride_src,
    __hip_bfloat16* __restrict__ dst, int dst_stride)
{
    __shared__ float tile[32][65];
    const int px0 = blockIdx.x * 64;
    const int c0  = blockIdx.y * 32;
    const int n   = blockIdx.z;
    const int tid = threadIdx.x;
    const int tx = tid & 63, ty = tid >> 6;
    #pragma unroll
    for (int i = 0; i < 8; ++i)
        tile[ty + i * 4][tx] = src[n * n_stride_src + (long)(c0 + ty + i * 4) * HW + px0 + tx];
    __syncthreads();
    const int ci = tid & 31, pxl = tid >> 5;
    #pragma unroll
    for (int j = 0; j < 8; ++j) {
        int px = pxl + j * 8;
        dst[((long)n * HW + px0 + px) * dst_stride + c0 + ci] = __float2bfloat16(tile[ci][px]);
    }
}

// ---------------------------------------------------------------------------
// weight convert: dst[t][co][ci] = bf16(src[co][ci][t])
// ---------------------------------------------------------------------------
__global__ __launch_bounds__(256) void wconv_kernel(
    const float* __restrict__ src, __hip_bfloat16* __restrict__ dst,
    int cout, int cin, int taps)
{
    int idx = blockIdx.x * 256 + threadIdx.x;
    if (idx >= cout * cin) return;
    int co = idx / cin, ci = idx % cin;
    for (int t = 0; t < taps; ++t)
        dst[((long)t * cout + co) * cin + ci] = __float2bfloat16(src[(long)idx * taps + t]);
}

// ---------------------------------------------------------------------------
// MFMA implicit-GEMM conv using mfma_f32_32x32x16_bf16.
// TAPS=9: 3x3 pad=1, ci-chunk 16; TAPS=1: 1x1, ci-chunk 32 (2 k-steps).
// 256 thr = 4 waves; tile co=64 (2 M-frags) x 4 rows x 96 cols (3 N-frags).
// LDS: input dbuf + weight dbuf = 76.8/57.3 KB -> 2 blocks/CU.
// SLOT SWIZZLE (R12 fix): bank(slot)=4*slot mod 32, so slots equal mod 8
// share a bank group; the plain layout put lanes {0,8,16,24} in ONE group
// (4-way conflict, 1.77e7 counted). Now T=(px>>3)*QD+q and
// slot = T*8 + ((px&7) ^ (T&7)) — low-3 bits are a permutation within each
// T-block, distinct across the conflicting lane set. Writer decodes inverse
// (px = g8*8 + (c ^ (T&7))); LDS dest stays linear (rule: swizzle source+
// reader together, never the gload_lds dest).
// Counted per-wave vmcnt. SPLIT fixup fires when (ch+2)==CROSS;
// dAB = (B - A) - (CROSS-1)*ADV.
// ---------------------------------------------------------------------------
template<int CIN, int TAPS, bool SPLIT>
__global__ __launch_bounds__(256, 2) void mfma_conv(
    const __hip_bfloat16* __restrict__ in_a,
    const __hip_bfloat16* __restrict__ in_b,
    const __hip_bfloat16* __restrict__ w_t,
    const float* __restrict__ bias,
    float* __restrict__ out_nchw, long nchw_nstride,
    __hip_bfloat16* __restrict__ out_nhwc, int nhwc_stride,
    int cout,
    const float* __restrict__ bng, const float* __restrict__ bnb,
    const float* __restrict__ pra,
    const __hip_bfloat16* __restrict__ zeropage)
{
    constexpr int KSTEPS = (TAPS == 1) ? 2 : 1;
    constexpr int QD     = 2 * KSTEPS;           // 16B ci-slots per pixel
    constexpr int CICH   = 16 * KSTEPS;          // ci per chunk
    constexpr int ROWS = (TAPS == 9) ? 6 : 4;
    constexpr int COLS = (TAPS == 9) ? 98 : 96;
    constexpr int HOFF = (TAPS == 9) ? 1 : 0;
    constexpr int PSTR = SPLIT ? 256 : CIN;
    constexpr int GP        = (COLS + 7) / 8;    // 13 / 12 pixel-groups
    constexpr int ROWSLOTS  = GP * 8 * QD;       // 208 / 384
    constexpr int IN_SLOTS  = ROWS * ROWSLOTS;   // 1248 / 1536
    constexpr int IN_BYTES  = IN_SLOTS * 16;     // 19968 / 24576
    constexpr int WTAP      = 64 * QD;           // slots per tap (128 / 256)
    constexpr int W_SLOTS   = TAPS * WTAP;       // 1152 / 256
    constexpr int BUF       = IN_BYTES + W_SLOTS * 16;  // 38400 / 28672
    constexpr int NCHUNK    = CIN / CICH;
    constexpr int FULL_IN = IN_SLOTS / 256;
    constexpr int IN_TAIL = IN_SLOTS % 256;
    constexpr int IT_IN   = FULL_IN + (IN_TAIL ? 1 : 0);
    constexpr int FULL_W  = W_SLOTS / 256;
    constexpr int W_TAIL  = W_SLOTS % 256;
    constexpr int IT_W    = FULL_W + (W_TAIL ? 1 : 0);
    constexpr int CROSS   = 256 / CICH;          // SPLIT crossing chunk
    constexpr long ADV    = 2 * CICH;            // bytes per chunk

    extern __shared__ __align__(16) char lds[];  // 2*BUF

    const int h0   = blockIdx.x * 4;
    const int cob  = blockIdx.y * 64;
    const int n    = blockIdx.z;
    const int tid  = threadIdx.x;
    const int lane = tid & 63;
    const int wave = tid >> 6;
    const int l31  = lane & 31;
    const int lq   = lane >> 5;
    const int g3   = l31 >> 3, c7 = l31 & 7;

    const long dAB = SPLIT ? ((const char*)in_b - (const char*)in_a - (CROSS - 1) * ADV) : 0;

    // ---- input staging pointers (swizzled decode: px = g8*8 + (c ^ (T&7))) --
    const char* inptr[IT_IN];
    int inval[IT_IN];
    #pragma unroll
    for (int t = 0; t < IT_IN; ++t) {
        int seg = tid + t * 256;
        int s2 = (seg < IN_SLOTS) ? seg : 0;
        int r  = s2 / ROWSLOTS;
        int sl = s2 - r * ROWSLOTS;
        int T  = sl >> 3, c = sl & 7;
        int q  = T & (QD - 1);
        int g8 = T / QD;
        int px = g8 * 8 + (c ^ (T & 7));
        int h = h0 + r - HOFF, w = px - HOFF;
        bool valid = (px < COLS) && (h >= 0 && h < IMG && w >= 0 && w < IMG);
        inptr[t] = valid
            ? (const char*)(in_a + ((long)n * HW + h * IMG + w) * PSTR + q * 8)
            : (const char*)zeropage;
        inval[t] = valid ? 1 : 0;
    }
    // ---- weight staging pointers (same swizzled decode on co) ----
    const char* wptr[IT_W];
    #pragma unroll
    for (int t = 0; t < IT_W; ++t) {
        int seg = tid + t * 256;
        int s2 = (seg < W_SLOTS) ? seg : 0;
        int tap = s2 / WTAP;
        int sl  = s2 - tap * WTAP;
        int T = sl >> 3, c = sl & 7;
        int q = T & (QD - 1);
        int co = (T / QD) * 8 + (c ^ (T & 7));
        wptr[t] = (const char*)(w_t + ((long)tap * cout + cob + co) * CIN + q * 8);
    }

    auto stage = [&](int bb, long adv) {
        char* ib = lds + bb * BUF;
        char* wb = ib + IN_BYTES;
        #pragma unroll
        for (int t = 0; t < FULL_IN; ++t) {
            gload16(inptr[t], ib + (tid + t * 256) * 16);
            if (inval[t]) inptr[t] += adv;
        }
        if (IN_TAIL) {
            if (tid < IN_TAIL) {
                gload16(inptr[IT_IN - 1], ib + (tid + FULL_IN * 256) * 16);
                if (inval[IT_IN - 1]) inptr[IT_IN - 1] += adv;
            }
        }
        #pragma unroll
        for (int t = 0; t < FULL_W; ++t) {
            gload16(wptr[t], wb + (tid + t * 256) * 16);
            wptr[t] += ADV;
        }
        if (W_TAIL) {
            if (tid < W_TAIL) {
                gload16(wptr[IT_W - 1], wb + (tid + FULL_W * 256) * 16);
                wptr[IT_W - 1] += ADV;
            }
        }
    };

    f32x16 acc[2][3];
    #pragma unroll
    for (int mf = 0; mf < 2; ++mf)
        #pragma unroll
        for (int nf = 0; nf < 3; ++nf)
            #pragma unroll
            for (int e = 0; e < 16; ++e) acc[mf][nf][e] = 0.f;

    stage(0, ADV);
    WAITVN(0); BARX();

    for (int ch = 0; ch < NCHUNK; ++ch) {
        if (ch + 1 < NCHUNK) {
            long adv = (SPLIT && (ch + 2) == CROSS) ? dAB : ADV;   // fixup = advance #(ch+2)
            stage((ch + 1) & 1, adv);
            if constexpr (TAPS == 9) {
                if (wave < 2) { WAITVN(10); } else { WAITVN(9); }
            } else {
                WAITVN(7);
            }
        } else {
            WAITVN(0);
        }
        BARX();

        const char* ib = lds + (ch & 1) * BUF;
        const char* wb = ib + IN_BYTES;
        const int rowbase = wave;   // + g below
        __builtin_amdgcn_s_setprio(1);
        #pragma unroll
        for (int tap = 0; tap < TAPS; ++tap) {
            const int g  = (TAPS == 9) ? tap / 3 : 0;
            const int kx = (TAPS == 9) ? tap % 3 : 0;
            #pragma unroll
            for (int ks = 0; ks < KSTEPS; ++ks) {
                const int q = ks * 2 + lq;
                const int Ta0 = g3 * QD + q;
                const int Ta1 = (4 + g3) * QD + q;
                bf16x8 a0 = *(const bf16x8*)(wb + (tap * WTAP + Ta0 * 8 + (c7 ^ (Ta0 & 7))) * 16);
                bf16x8 a1 = *(const bf16x8*)(wb + (tap * WTAP + Ta1 * 8 + (c7 ^ (Ta1 & 7))) * 16);
                #pragma unroll
                for (int nf = 0; nf < 3; ++nf) {
                    const int px = nf * 32 + kx + l31;
                    const int Tb = (px >> 3) * QD + q;
                    const int slot = Tb * 8 + ((px & 7) ^ (Tb & 7));
                    bf16x8 b = *(const bf16x8*)(ib + ((rowbase + g) * ROWSLOTS + slot) * 16);
                    acc[0][nf] = __builtin_amdgcn_mfma_f32_32x32x16_bf16(a0, b, acc[0][nf], 0, 0, 0);
                    acc[1][nf] = __builtin_amdgcn_mfma_f32_32x32x16_bf16(a1, b, acc[1][nf], 0, 0, 0);
                }
            }
        }
        __builtin_amdgcn_s_setprio(0);
        BARX();
    }

    // ---- epilogue (32x32 C/D: col=lane&31, row=(r&3)+8*(r>>2)+4*(lane>>5)) --
    const int row = h0 + wave;
    #pragma unroll
    for (int mf = 0; mf < 2; ++mf) {
        #pragma unroll
        for (int rr = 0; rr < 4; ++rr) {
            const int co = cob + mf * 32 + rr * 8 + lq * 4;
            float bs[4], g4[4], b4[4], p4[4];
            #pragma unroll
            for (int j = 0; j < 4; ++j) bs[j] = bias ? bias[co + j] : 0.f;
            if (bng) {
                #pragma unroll
                for (int j = 0; j < 4; ++j) { g4[j] = bng[co + j]; b4[j] = bnb[co + j]; p4[j] = pra[co + j]; }
            }
            #pragma unroll
            for (int nf = 0; nf < 3; ++nf) {
                const int px = nf * 32 + l31;
                const long pix = (long)row * IMG + px;
                float v[4];
                #pragma unroll
                for (int j = 0; j < 4; ++j) {
                    v[j] = acc[mf][nf][rr * 4 + j] + bs[j];
                    if (bng) {
                        v[j] = v[j] * g4[j] + b4[j];
                        v[j] = (v[j] >= 0.f) ? v[j] : p4[j] * v[j];
                    }
                }
                if (out_nchw) {
                    #pragma unroll
                    for (int j = 0; j < 4; ++j)
                        out_nchw[(long)n * nchw_nstride + (long)(co + j) * HW + pix] = v[j];
                }
                if (out_nhwc) {
                    union { __hip_bfloat16 h[4]; uint2 u; } pk;
                    #pragma unroll
                    for (int j = 0; j < 4; ++j) pk.h[j] = __float2bfloat16(v[j]);
                    *reinterpret_cast<uint2*>(&out_nhwc[((long)n * HW + pix) * nhwc_stride + co]) = pk.u;
                }
            }
        }
    }
}

// ---------------------------------------------------------------------------
// pool_to_3x3 for x1 (xd ch 0..127) and y1 (y ch 0..127)
// ---------------------------------------------------------------------------
__global__ __launch_bounds__(256) void pool_kernel(
    const float* __restrict__ xd, const float* __restrict__ y,
    float* __restrict__ gl, float* __restrict__ py)
{
    const int c = blockIdx.x, n = blockIdx.y, which = blockIdx.z;
    const int tid = threadIdx.x;
    const float* src = (which == 0) ? (xd + ((long)n * 256 + c) * HW)
                                    : (y  + ((long)n * 256 + c) * HW);
    float local[9];
    #pragma unroll
    for (int k = 0; k < 9; ++k) local[k] = 0.f;
    for (int i = tid; i < HW; i += 256) {
        int h = i / 96, w = i % 96;
        local[(h / 32) * 3 + (w / 32)] += src[i];
    }
    __shared__ float red[9][4];
    const int wv = tid >> 6, lane = tid & 63;
    #pragma unroll
    for (int k = 0; k < 9; ++k) {
        float v = local[k];
        for (int off = 32; off > 0; off >>= 1) v += __shfl_down(v, off, 64);
        if (lane == 0) red[k][wv] = v;
    }
    __syncthreads();
    if (tid < 9) {
        float s = (red[tid][0] + red[tid][1] + red[tid][2] + red[tid][3]) * (1.f / 1024.f);
        float* dst = (which == 0) ? gl : py;
        dst[((long)n * 128 + c) * 9 + tid] = s;
    }
}

// ---------------------------------------------------------------------------
__global__ __launch_bounds__(128) void attkc_kernel(
    const float* __restrict__ gl, const float* __restrict__ py,
    const float* __restrict__ w_ce, const float* __restrict__ w_gd,
    const float* __restrict__ bng, const float* __restrict__ bnb,
    const float* __restrict__ w_kc, const float* __restrict__ b_kc,
    float* __restrict__ kc)
{
    const int n = blockIdx.x, c = threadIdx.x;
    __shared__ float py_s[128][9];
    #pragma unroll
    for (int k = 0; k < 9; ++k) py_s[c][k] = py[((long)n * 128 + c) * 9 + k];
    __syncthreads();
    float g[9];
    #pragma unroll
    for (int k = 0; k < 9; ++k) g[k] = gl[((long)n * 128 + c) * 9 + k];
    float t[5];
    #pragma unroll
    for (int l = 0; l < 5; ++l) {
        float s = 0.f;
        #pragma unroll
        for (int k = 0; k < 9; ++k) s += g[k] * w_ce[l * 9 + k];
        s = s * bng[c] + bnb[c];
        t[l] = s > 0.f ? s : 0.f;
    }
    float att[9];
    #pragma unroll
    for (int k = 0; k < 9; ++k) {
        float s = 0.f;
        #pragma unroll
        for (int l = 0; l < 5; ++l) s += t[l] * w_gd[k * 5 + l];
        att[k] = 1.f / (1.f + expf(-s));
    }
    float kc0[9];
    float bk = b_kc[c];
    #pragma unroll
    for (int k = 0; k < 9; ++k) kc0[k] = bk;
    for (int c2 = 0; c2 < 128; ++c2) {
        float wv = w_kc[c * 128 + c2];
        #pragma unroll
        for (int k = 0; k < 9; ++k) kc0[k] += wv * py_s[c2][k];
    }
    #pragma unroll
    for (int k = 0; k < 9; ++k)
        kc[((long)n * 128 + c) * 9 + k] = kc0[k] * att[k];
}

// ---------------------------------------------------------------------------
// channel_after, NHWC form: reads cat_x (bf16 NHWC ch0..127 = x1), kc in regs,
// writes catfb ch0..127 (bf16 NHWC). Block = one row h; thread: 8 ch x 16 px.
// ---------------------------------------------------------------------------
__global__ __launch_bounds__(256) void channel_nhwc_kernel(
    const __hip_bfloat16* __restrict__ catx, const float* __restrict__ kc,
    __hip_bfloat16* __restrict__ catfb)
{
    const int h  = blockIdx.x;
    const int n  = blockIdx.y;
    const int cg = (threadIdx.x & 15) * 8;
    const int w0 = threadIdx.x >> 4;
    float k9[8][9];
    #pragma unroll
    for (int j = 0; j < 8; ++j)
        #pragma unroll
        for (int t = 0; t < 9; ++t) k9[j][t] = kc[((long)n * 128 + cg + j) * 9 + t];
    const long pbase = (long)n * HW;
    for (int it = 0; it < 6; ++it) {
        const int w = w0 + it * 16;
        float acc[8];
        #pragma unroll
        for (int j = 0; j < 8; ++j) acc[j] = 0.f;
        #pragma unroll
        for (int ky = 0; ky < 3; ++ky) {
            const int hh = h + ky - 1;
            if (hh < 0 || hh >= IMG) continue;
            #pragma unroll
            for (int kx = 0; kx < 3; ++kx) {
                const int ww = w + kx - 1;
                if (ww < 0 || ww >= IMG) continue;
                bf16x8 v = *reinterpret_cast<const bf16x8*>(
                    &catx[(pbase + hh * IMG + ww) * 256 + cg]);
                #pragma unroll
                for (int j = 0; j < 8; ++j)
                    acc[j] += k9[j][ky * 3 + kx] * (float)v[j];
            }
        }
        union { __hip_bfloat16 hh[8]; uint4 u; } pk;
        #pragma unroll
        for (int j = 0; j < 8; ++j) pk.hh[j] = __float2bfloat16(acc[j]);
        *reinterpret_cast<uint4*>(&catfb[(pbase + h * IMG + w) * 256 + cg]) = pk.u;
    }
}

// ---------------------------------------------------------------------------
// ks = 1x1 conv 128->9 on ksmid [N][128][HW] fp32
// ---------------------------------------------------------------------------
__global__ __launch_bounds__(256) void ks_kernel(
    const float* __restrict__ ksmid, const float* __restrict__ w_ks2,
    const float* __restrict__ b_ks2, float* __restrict__ ks)
{
    __shared__ float w_s[9 * 128];
    const int tid = threadIdx.x;
    for (int i = tid; i < 1152; i += 256) w_s[i] = w_ks2[i];
    __syncthreads();
    const int p = blockIdx.x * 256 + tid;
    const int n = blockIdx.y;
    float acc[9];
    #pragma unroll
    for (int k = 0; k < 9; ++k) acc[k] = b_ks2[k];
    for (int c = 0; c < 128; ++c) {
        float v = ksmid[((long)n * 128 + c) * HW + p];
        #pragma unroll
        for (int k = 0; k < 9; ++k) acc[k] += w_s[k * 128 + c] * v;
    }
    #pragma unroll
    for (int k = 0; k < 9; ++k) ks[((long)n * 9 + k) * HW + p] = acc[k];
}

// ---------------------------------------------------------------------------
// ksp = conv3x3(x2, w_sp1, pad=1) -> 1 channel, NHWC data-parallel.
// ---------------------------------------------------------------------------
__global__ __launch_bounds__(256) void ksp_nhwc_kernel(
    const __hip_bfloat16* __restrict__ catx, const float* __restrict__ w_sp1,
    float* __restrict__ ksp)
{
    __shared__ float w_s[9][128];
    const int tid = threadIdx.x;
    for (int i = tid; i < 1152; i += 256) {
        int ci = i / 9, tap = i % 9;            // src layout [ci][tap]
        w_s[tap][ci] = w_sp1[i];
    }
    __syncthreads();
    const int p = blockIdx.x * 256 + tid;
    const int n = blockIdx.y;
    const int h = p / 96, w = p % 96;
    const long pbase = (long)n * HW;
    float acc = 0.f;
    #pragma unroll
    for (int ky = 0; ky < 3; ++ky) {
        const int hh = h + ky - 1;
        if (hh < 0 || hh >= IMG) continue;
        #pragma unroll
        for (int kx = 0; kx < 3; ++kx) {
            const int ww = w + kx - 1;
            if (ww < 0 || ww >= IMG) continue;
            const int tap = ky * 3 + kx;
            const __hip_bfloat16* row = &catx[(pbase + hh * IMG + ww) * 256 + 128];
            #pragma unroll
            for (int vq = 0; vq < 16; ++vq) {
                bf16x8 v = *reinterpret_cast<const bf16x8*>(&row[vq * 8]);
                #pragma unroll
                for (int j = 0; j < 8; ++j)
                    acc += w_s[tap][vq * 8 + j] * (float)v[j];
            }
        }
    }
    ksp[pbase + p] = acc;
}

// ---------------------------------------------------------------------------
__global__ __launch_bounds__(256) void sp_kernel(
    const float* __restrict__ ksp, const float* __restrict__ w_sp,
    float* __restrict__ sp)
{
    const int p = blockIdx.x * 256 + threadIdx.x;
    const int n = blockIdx.y;
    const int h = p / 96, w = p % 96;
    const float* kp = ksp + (long)n * HW;
    float acc = 0.f;
    #pragma unroll
    for (int dy = 0; dy < 3; ++dy)
        #pragma unroll
        for (int dx = 0; dx < 3; ++dx) {
            int hh = h + dy - 1, ww = w + dx - 1;
            if (hh < 0 || hh >= 96 || ww < 0 || ww >= 96) continue;
            float s = 0.f, m = -1e30f;
            #pragma unroll
            for (int iy = 0; iy < 3; ++iy)
                #pragma unroll
                for (int ix = 0; ix < 3; ++ix) {
                    int h2 = hh + iy - 1, w2 = ww + ix - 1;
                    float v = (h2 >= 0 && h2 < 96 && w2 >= 0 && w2 < 96) ? kp[h2 * 96 + w2] : 0.f;
                    s += v; m = fmaxf(m, v);
                }
            acc += w_sp[dy * 3 + dx] * (s * (1.f / 9.f)) + w_sp[9 + dy * 3 + dx] * m;
        }
    sp[(long)n * HW + p] = 1.f / (1.f + expf(-acc));
}

// ---------------------------------------------------------------------------
// spatial_after -> catfb ch128..255 (raw-reshape gather; cc = p/72)
// ---------------------------------------------------------------------------
__global__ __launch_bounds__(256) void spatial_kernel(
    const float* __restrict__ xd, const float* __restrict__ ks,
    const float* __restrict__ sp, __hip_bfloat16* __restrict__ catfb)
{
    const int cc = blockIdx.x;
    const int n  = blockIdx.y;
    const int tid = threadIdx.x;
    __shared__ float plane[HW];
    const float* src = xd + ((long)n * 256 + 128 + cc) * HW;
    for (int i = tid; i < HW / 4; i += 256)
        *reinterpret_cast<float4*>(&plane[i * 4]) = *reinterpret_cast<const float4*>(&src[i * 4]);
    __syncthreads();
    const int c  = tid & 127;
    const int pr = tid >> 7;
    const int c9 = c * 9;
    for (int j = 0; j < 36; ++j) {
        const int pl = pr + j * 2;
        const int p  = cc * 72 + pl;
        float spv = sp[(long)n * HW + p];
        float kv[9];
        #pragma unroll
        for (int k = 0; k < 9; ++k) kv[k] = ks[((long)n * 9 + k) * HW + p] * spv;
        const int base = pl * 1152 + c9;
        int kk0 = base / 9216;
        int r20 = base - kk0 * 9216;
        int h20 = r20 / 96;
        int w20 = r20 - h20 * 96;
        float acc = 0.f;
        #pragma unroll
        for (int k = 0; k < 9; ++k) {
            int kk = kk0, h2 = h20, w2 = w20 + k;
            if (w2 >= 96) { h2 += 1; w2 -= 96; }
            if (h2 >= 96) { kk += 1; h2 -= 96; }
            int hh = h2 + kk / 3 - 1;
            int ww = w2 + kk % 3 - 1;
            float v = (hh >= 0 && hh < 96 && ww >= 0 && ww < 96) ? plane[hh * 96 + ww] : 0.f;
            acc += v * kv[k];
        }
        catfb[((long)n * HW + p) * 256 + 128 + c] = __float2bfloat16(acc);
    }
}

// ---------------------------------------------------------------------------
extern "C" void kernel_launch(void* const* d_in, const int* in_sizes, int n_in,
                              void* d_out, int out_size, void* d_ws, size_t ws_size,
                              hipStream_t stream)
{
    const float* x      = (const float*)d_in[0];
    const float* y      = (const float*)d_in[1];
    const float* w_down = (const float*)d_in[2];
    const float* b_down = (const float*)d_in[3];
    const float* w_ce   = (const float*)d_in[4];
    const float* w_gd   = (const float*)d_in[5];
    const float* bn_g   = (const float*)d_in[6];
    const float* bn_b   = (const float*)d_in[7];
    const float* w_kc   = (const float*)d_in[8];
    const float* b_kc   = (const float*)d_in[9];
    const float* w_ks1  = (const float*)d_in[10];
    const float* b_ks1  = (const float*)d_in[11];
    const float* w_ks2  = (const float*)d_in[12];
    const float* b_ks2  = (const float*)d_in[13];
    const float* w_sp1  = (const float*)d_in[14];
    const float* w_sp   = (const float*)d_in[15];
    const float* w_fb   = (const float*)d_in[16];
    const float* b_fb   = (const float*)d_in[17];
    const float* w_fuse = (const float*)d_in[18];
    const float* bn2_g  = (const float*)d_in[19];
    const float* bn2_b  = (const float*)d_in[20];
    const float* prelu  = (const float*)d_in[21];
    float* out = (float*)d_out;
    char* ws = (char*)d_ws;

    const long HWl = HW;
    // --- workspace layout ---
    float* xd = (float*)ws;                               ws += 8L * 256 * HWl * 4;  // 75.5MB
    // region2: 75.5MB. Timeline: x_t (whole) -> dead after conv1x1;
    //          then ksmid (lower, fp32) until ks_kernel; catfb (upper);
    //          finally cat_r1 (lower) written by fb conv.
    char* region2 = ws;                                   ws += 8L * HWl * 512 * 2;
    __hip_bfloat16* x_t    = (__hip_bfloat16*)region2;            // [N][HW][512] bf16
    __hip_bfloat16* cat_r1 = (__hip_bfloat16*)region2;            // [N][HW][256] bf16
    float*          ksmid  = (float*)region2;                     // [N][128][HW] fp32
    __hip_bfloat16* catfb  = (__hip_bfloat16*)(region2 + 8L * HWl * 256 * 2); // [N][HW][256]
    __hip_bfloat16* cat_x  = (__hip_bfloat16*)ws;         ws += 8L * HWl * 256 * 2;  // 37.7MB
    __hip_bfloat16* y2t    = (__hip_bfloat16*)ws;         ws += 8L * HWl * 128 * 2;  // 18.9MB
    __hip_bfloat16* wdown_bf = (__hip_bfloat16*)ws;       ws += 1L * 256 * 512 * 2;
    __hip_bfloat16* wks1_bf  = (__hip_bfloat16*)ws;       ws += 9L * 128 * 128 * 2;
    __hip_bfloat16* wfb_bf   = (__hip_bfloat16*)ws;       ws += 9L * 256 * 256 * 2;
    __hip_bfloat16* wfuse_bf = (__hip_bfloat16*)ws;       ws += 9L * 256 * 512 * 2;
    float* ks   = (float*)ws;  ws += 8L * 9 * HWl * 4;
    float* ksp  = (float*)ws;  ws += 8L * HWl * 4;
    float* spb  = (float*)ws;  ws += 8L * HWl * 4;
    float* gl   = (float*)ws;  ws += 8L * 128 * 9 * 4;
    float* py   = (float*)ws;  ws += 8L * 128 * 9 * 4;
    float* kc   = (float*)ws;  ws += 8L * 128 * 9 * 4;
    __hip_bfloat16* zp = (__hip_bfloat16*)ws;  ws += 256;

    (void)hipMemsetAsync((void*)zp, 0, 256, stream);

    // weight conversions
    wconv_kernel<<<dim3(512), 256, 0, stream>>>(w_down, wdown_bf, 256, 512, 1);
    wconv_kernel<<<dim3(64),  256, 0, stream>>>(w_ks1,  wks1_bf,  128, 128, 9);
    wconv_kernel<<<dim3(256), 256, 0, stream>>>(w_fb,   wfb_bf,   256, 256, 9);
    wconv_kernel<<<dim3(512), 256, 0, stream>>>(w_fuse, wfuse_bf, 256, 512, 9);

    // x -> NHWC bf16, then 1x1 down conv -> xd (fp32 NCHW) + cat_x (bf16 NHWC)
    nchw2nhwc_kernel<<<dim3(144, 16, 8), 256, 0, stream>>>(x, 512L * HWl, x_t, 512);
    mfma_conv<512, 1, false><<<dim3(24, 4, 8), 256, 57344, stream>>>(
        x_t, nullptr, wdown_bf, b_down, xd, 256L * HWl, cat_x, 256, 256,
        nullptr, nullptr, nullptr, zp);

    // y2 -> NHWC bf16
    nchw2nhwc_kernel<<<dim3(144, 4, 8), 256, 0, stream>>>(y + 128L * HWl, 256L * HWl, y2t, 128);

    // pools / attention
    pool_kernel<<<dim3(128, 8, 2), 256, 0, stream>>>(xd, y, gl, py);
    attkc_kernel<<<dim3(8), 128, 0, stream>>>(gl, py, w_ce, w_gd, bn_g, bn_b, w_kc, b_kc, kc);

    // ks_mid = conv3x3(y2) -> ksmid fp32 (x_t dead now)
    mfma_conv<128, 9, false><<<dim3(24, 2, 8), 256, 76800, stream>>>(
        y2t, nullptr, wks1_bf, b_ks1, ksmid, 128L * HWl, nullptr, 0, 128,
        nullptr, nullptr, nullptr, zp);
    ks_kernel<<<dim3(36, 8), 256, 0, stream>>>(ksmid, w_ks2, b_ks2, ks);

    // ksp / sp  (ksp NHWC data-parallel from cat_x ch128..255)
    ksp_nhwc_kernel<<<dim3(36, 8), 256, 0, stream>>>(cat_x, w_sp1, ksp);
    sp_kernel<<<dim3(36, 8), 256, 0, stream>>>(ksp, w_sp, spb);

    // spatial_after -> catfb ch128..255 ; channel_after -> catfb ch0..127
    spatial_kernel<<<dim3(128, 8), 256, 0, stream>>>(xd, ks, spb, catfb);
    channel_nhwc_kernel<<<dim3(96, 8), 256, 0, stream>>>(cat_x, kc, catfb);

    // r1 = conv3x3(catfb, w_fb)+b -> cat_r1 (bf16 NHWC; ksmid dead)
    mfma_conv<256, 9, false><<<dim3(24, 4, 8), 256, 76800, stream>>>(
        catfb, nullptr, wfb_bf, b_fb, nullptr, 0, cat_r1, 256, 256,
        nullptr, nullptr, nullptr, zp);

    // out = prelu(bn(conv3x3([cat_x | cat_r1], w_fuse)))
    mfma_conv<512, 9, true><<<dim3(24, 4, 8), 256, 76800, stream>>>(
        cat_x, cat_r1, wfuse_bf, nullptr, out, 256L * HWl, nullptr, 0, 256,
        bn2_g, bn2_b, prelu, zp);
}

// Round 14
// 662.427 us; speedup vs baseline: 1.0654x; 1.0654x over previous
//
#include <hip/hip_runtime.h>
#include <hip/hip_bf16.h>
#include <math.h>

#define HW 9216
#define IMG 96

typedef __bf16 bf16x8 __attribute__((ext_vector_type(8)));
typedef float  f32x4  __attribute__((ext_vector_type(4)));

__device__ __forceinline__ void gload16(const void* g, void* l) {
    __builtin_amdgcn_global_load_lds((const unsigned int*)g, (unsigned int*)l, 16, 0, 0);
}

#define WAITVN(N) asm volatile("s_waitcnt vmcnt(" #N ")" ::: "memory")
#define BARX()    { asm volatile("" ::: "memory"); __builtin_amdgcn_s_barrier(); asm volatile("" ::: "memory"); }

// ---------------------------------------------------------------------------
// NCHW fp32 -> NHWC bf16 transpose/convert. grid (HW/64, cin/32, N)
// ---------------------------------------------------------------------------
__global__ __launch_bounds__(256) void nchw2nhwc_kernel(
    const float* __restrict__ src, long n_stride_src,
    __hip_bfloat16* __restrict__ dst, int dst_stride)
{
    __shared__ float tile[32][65];
    const int px0 = blockIdx.x * 64;
    const int c0  = blockIdx.y * 32;
    const int n   = blockIdx.z;
    const int tid = threadIdx.x;
    const int tx = tid & 63, ty = tid >> 6;
    #pragma unroll
    for (int i = 0; i < 8; ++i)
        tile[ty + i * 4][tx] = src[n * n_stride_src + (long)(c0 + ty + i * 4) * HW + px0 + tx];
    __syncthreads();
    const int ci = tid & 31, pxl = tid >> 5;
    #pragma unroll
    for (int j = 0; j < 8; ++j) {
        int px = pxl + j * 8;
        dst[((long)n * HW + px0 + px) * dst_stride + c0 + ci] = __float2bfloat16(tile[ci][px]);
    }
}

// ---------------------------------------------------------------------------
// all four weight conversions in ONE launch: dst[t][co][ci] = bf16(src[co][ci][t])
// grid (512, 4); blockIdx.y selects the tensor.
// ---------------------------------------------------------------------------
__global__ __launch_bounds__(256) void wconv_all_kernel(
    const float* __restrict__ w_down, const float* __restrict__ w_ks1,
    const float* __restrict__ w_fb,   const float* __restrict__ w_fuse,
    __hip_bfloat16* __restrict__ d_down, __hip_bfloat16* __restrict__ d_ks1,
    __hip_bfloat16* __restrict__ d_fb,   __hip_bfloat16* __restrict__ d_fuse)
{
    const float* src; __hip_bfloat16* dst; int cout, cin, taps;
    switch (blockIdx.y) {
        case 0:  src = w_down; dst = d_down; cout = 256; cin = 512; taps = 1; break;
        case 1:  src = w_ks1;  dst = d_ks1;  cout = 128; cin = 128; taps = 9; break;
        case 2:  src = w_fb;   dst = d_fb;   cout = 256; cin = 256; taps = 9; break;
        default: src = w_fuse; dst = d_fuse; cout = 256; cin = 512; taps = 9; break;
    }
    int idx = blockIdx.x * 256 + threadIdx.x;
    if (idx >= cout * cin) return;
    int co = idx / cin, ci = idx % cin;
    for (int t = 0; t < taps; ++t)
        dst[((long)t * cout + co) * cin + ci] = __float2bfloat16(src[(long)idx * taps + t]);
}

// ---------------------------------------------------------------------------
// MFMA implicit-GEMM conv (TAPS=9: 3x3 pad=1; TAPS=1: 1x1), bf16 in, fp32 acc.
// R10-proven geometry (best measured): 512 threads = 8 waves; tile co=32 x
// rows=8 x cols=96; ci-chunk 32; mfma 16x16x32. LDS: input dbuf (10x98 rows)
// + weight dbuf ([9][32][32]) = 162,304 B -> 1 block/CU, 2 waves/SIMD.
// Counted per-wave vmcnt keeps next-chunk stage in flight across the barrier.
// SPLIT: ptr fixup at chunk 7->8 staging, dAB = (B - A) - 448.
// ---------------------------------------------------------------------------
template<int CIN, int TAPS, bool SPLIT>
__global__ __launch_bounds__(512, 1) void mfma_conv(
    const __hip_bfloat16* __restrict__ in_a,
    const __hip_bfloat16* __restrict__ in_b,
    const __hip_bfloat16* __restrict__ w_t,
    const float* __restrict__ bias,
    float* __restrict__ out_nchw, long nchw_nstride,
    __hip_bfloat16* __restrict__ out_nhwc, int nhwc_stride,
    int cout,
    const float* __restrict__ bng, const float* __restrict__ bnb,
    const float* __restrict__ pra,
    const __hip_bfloat16* __restrict__ zeropage)
{
    constexpr int ROWS = (TAPS == 9) ? 10 : 8;      // staged rows
    constexpr int COLS = (TAPS == 9) ? 98 : 96;
    constexpr int HOFF = (TAPS == 9) ? 1 : 0;
    constexpr int PSTR = SPLIT ? 256 : CIN;
    constexpr int NSEG_IN = ROWS * COLS * 4;        // 3920 / 3072
    constexpr int NSEG_W  = TAPS * 32 * 4;          // 1152 / 128
    constexpr int IN_BYTES = NSEG_IN * 16;          // 62720 / 49152
    constexpr int BUF = IN_BYTES + NSEG_W * 16;     // 81152 / 51200
    constexpr int NCHUNK = CIN / 32;
    constexpr int FULL_IN = NSEG_IN / 512;          // 7 / 6
    constexpr int IN_TAIL = NSEG_IN % 512;          // 336 / 0
    constexpr int FULL_W  = NSEG_W / 512;           // 2 / 0
    constexpr int W_TAIL  = NSEG_W % 512;           // 128 / 128
    constexpr int IT_IN = FULL_IN + (IN_TAIL ? 1 : 0);
    constexpr int IT_W  = FULL_W + (W_TAIL ? 1 : 0);

    extern __shared__ __align__(16) char lds[];     // 2*BUF

    const int h0   = blockIdx.x * 8;
    const int cob  = blockIdx.y * 32;
    const int n    = blockIdx.z;
    const int tid  = threadIdx.x;
    const int lane = tid & 63;
    const int wave = tid >> 6;
    const int l16  = lane & 15, lg = lane >> 4;

    const long dAB = SPLIT ? ((const char*)in_b - (const char*)in_a - 448) : 0;

    // ---- input staging pointers (advance 64B per ci-chunk) ----
    const char* inptr[IT_IN];
    int inval[IT_IN];
    #pragma unroll
    for (int t = 0; t < IT_IN; ++t) {
        int seg = tid + t * 512;
        int s2 = (seg < NSEG_IN) ? seg : 0;
        int pix = s2 >> 2, qp = s2 & 3;
        int r = pix / COLS, c = pix % COLS;
        int h = h0 + r - HOFF, w = c - HOFF;
        int q = qp ^ ((c >> 1) & 3);                 // inverse-swizzled source slot
        bool valid = (h >= 0 && h < IMG && w >= 0 && w < IMG);
        inptr[t] = valid
            ? (const char*)(in_a + ((long)n * HW + h * IMG + w) * PSTR + q * 8)
            : (const char*)zeropage;
        inval[t] = valid ? 1 : 0;
    }
    // ---- weight staging pointers ----
    const char* wptr[IT_W];
    #pragma unroll
    for (int t = 0; t < IT_W; ++t) {
        int seg = tid + t * 512;
        int s2 = (seg < NSEG_W) ? seg : 0;
        int tap = s2 >> 7, rem = s2 & 127;
        int co = rem >> 2, qp = rem & 3;
        int q = qp ^ ((co >> 1) & 3);
        wptr[t] = (const char*)(w_t + ((long)tap * cout + cob + co) * CIN + q * 8);
    }

    auto stage = [&](int bb, long adv) {
        char* ib = lds + bb * BUF;
        char* wb = ib + IN_BYTES;
        #pragma unroll
        for (int t = 0; t < FULL_IN; ++t) {
            gload16(inptr[t], ib + (tid + t * 512) * 16);
            if (inval[t]) inptr[t] += adv;
        }
        if (IN_TAIL) {
            if (tid < IN_TAIL) {
                gload16(inptr[IT_IN - 1], ib + (tid + FULL_IN * 512) * 16);
                if (inval[IT_IN - 1]) inptr[IT_IN - 1] += adv;
            }
        }
        #pragma unroll
        for (int t = 0; t < FULL_W; ++t) {
            gload16(wptr[t], wb + (tid + t * 512) * 16);
            wptr[t] += 64;
        }
        if (W_TAIL) {
            if (tid < W_TAIL) {
                gload16(wptr[IT_W - 1], wb + (tid + FULL_W * 512) * 16);
                wptr[IT_W - 1] += 64;
            }
        }
    };

    f32x4 acc[2][6];
    #pragma unroll
    for (int m = 0; m < 2; ++m)
        #pragma unroll
        for (int nf = 0; nf < 6; ++nf) acc[m][nf] = (f32x4){0.f, 0.f, 0.f, 0.f};

    const int qa = lg ^ ((l16 >> 1) & 3);
    const int a_off = l16 * 64 + qa * 16;

    stage(0, 64);
    WAITVN(0); BARX();

    for (int ch = 0; ch < NCHUNK; ++ch) {
        if (ch + 1 < NCHUNK) {
            long adv = (SPLIT && (ch + 1) == 7) ? dAB : 64;
            stage((ch + 1) & 1, adv);
            // per-wave count of loads just issued -> previous stage drained,
            // new stage stays in flight across the barrier
            if constexpr (TAPS == 9) {
                if (wave < 2) { WAITVN(11); } else if (wave < 6) { WAITVN(10); } else { WAITVN(9); }
            } else {
                if (wave < 2) { WAITVN(7); } else { WAITVN(6); }
            }
        } else {
            WAITVN(0);
        }
        BARX();

        const char* ib = lds + (ch & 1) * BUF;
        const char* wb = ib + IN_BYTES;
        __builtin_amdgcn_s_setprio(1);
        #pragma unroll
        for (int tap = 0; tap < TAPS; ++tap) {
            const int g = (TAPS == 9) ? tap / 3 : 0;
            const int kx = (TAPS == 9) ? tap % 3 : 0;
            bf16x8 a0 = *(const bf16x8*)(wb + tap * 2048 + a_off);
            bf16x8 a1 = *(const bf16x8*)(wb + tap * 2048 + 1024 + a_off);
            #pragma unroll
            for (int nf = 0; nf < 6; ++nf) {
                const int c = nf * 16 + l16 + kx;
                const int qb = lg ^ ((c >> 1) & 3);
                bf16x8 b = *(const bf16x8*)(ib + ((wave + g) * COLS + c) * 64 + qb * 16);
                acc[0][nf] = __builtin_amdgcn_mfma_f32_16x16x32_bf16(a0, b, acc[0][nf], 0, 0, 0);
                acc[1][nf] = __builtin_amdgcn_mfma_f32_16x16x32_bf16(a1, b, acc[1][nf], 0, 0, 0);
            }
        }
        __builtin_amdgcn_s_setprio(0);
        BARX();
    }

    // ---- epilogue ----
    const int hrow = h0 + wave;
    #pragma unroll
    for (int m = 0; m < 2; ++m) {
        const int co = cob + m * 16 + lg * 4;
        float bs[4], g4[4], b4[4], p4[4];
        #pragma unroll
        for (int r = 0; r < 4; ++r) bs[r] = bias ? bias[co + r] : 0.f;
        if (bng) {
            #pragma unroll
            for (int r = 0; r < 4; ++r) { g4[r] = bng[co + r]; b4[r] = bnb[co + r]; p4[r] = pra[co + r]; }
        }
        #pragma unroll
        for (int nf = 0; nf < 6; ++nf) {
            const int wcol = nf * 16 + l16;
            const long px = (long)hrow * IMG + wcol;
            float v[4];
            #pragma unroll
            for (int r = 0; r < 4; ++r) {
                v[r] = acc[m][nf][r] + bs[r];
                if (bng) {
                    v[r] = v[r] * g4[r] + b4[r];
                    v[r] = (v[r] >= 0.f) ? v[r] : p4[r] * v[r];
                }
            }
            if (out_nchw) {
                #pragma unroll
                for (int r = 0; r < 4; ++r)
                    out_nchw[(long)n * nchw_nstride + (long)(co + r) * HW + px] = v[r];
            }
            if (out_nhwc) {
                union { __hip_bfloat16 h[4]; uint2 u; } pk;
                #pragma unroll
                for (int r = 0; r < 4; ++r) pk.h[r] = __float2bfloat16(v[r]);
                *reinterpret_cast<uint2*>(&out_nhwc[((long)n * HW + px) * nhwc_stride + co]) = pk.u;
            }
        }
    }
}

// ---------------------------------------------------------------------------
// pool_to_3x3 for x1 (xd ch 0..127) and y1 (y ch 0..127)
// ---------------------------------------------------------------------------
__global__ __launch_bounds__(256) void pool_kernel(
    const float* __restrict__ xd, const float* __restrict__ y,
    float* __restrict__ gl, float* __restrict__ py)
{
    const int c = blockIdx.x, n = blockIdx.y, which = blockIdx.z;
    const int tid = threadIdx.x;
    const float* src = (which == 0) ? (xd + ((long)n * 256 + c) * HW)
                                    : (y  + ((long)n * 256 + c) * HW);
    float local[9];
    #pragma unroll
    for (int k = 0; k < 9; ++k) local[k] = 0.f;
    for (int i = tid; i < HW; i += 256) {
        int h = i / 96, w = i % 96;
        local[(h / 32) * 3 + (w / 32)] += src[i];
    }
    __shared__ float red[9][4];
    const int wv = tid >> 6, lane = tid & 63;
    #pragma unroll
    for (int k = 0; k < 9; ++k) {
        float v = local[k];
        for (int off = 32; off > 0; off >>= 1) v += __shfl_down(v, off, 64);
        if (lane == 0) red[k][wv] = v;
    }
    __syncthreads();
    if (tid < 9) {
        float s = (red[tid][0] + red[tid][1] + red[tid][2] + red[tid][3]) * (1.f / 1024.f);
        float* dst = (which == 0) ? gl : py;
        dst[((long)n * 128 + c) * 9 + tid] = s;
    }
}

// ---------------------------------------------------------------------------
__global__ __launch_bounds__(128) void attkc_kernel(
    const float* __restrict__ gl, const float* __restrict__ py,
    const float* __restrict__ w_ce, const float* __restrict__ w_gd,
    const float* __restrict__ bng, const float* __restrict__ bnb,
    const float* __restrict__ w_kc, const float* __restrict__ b_kc,
    float* __restrict__ kc)
{
    const int n = blockIdx.x, c = threadIdx.x;
    __shared__ float py_s[128][9];
    #pragma unroll
    for (int k = 0; k < 9; ++k) py_s[c][k] = py[((long)n * 128 + c) * 9 + k];
    __syncthreads();
    float g[9];
    #pragma unroll
    for (int k = 0; k < 9; ++k) g[k] = gl[((long)n * 128 + c) * 9 + k];
    float t[5];
    #pragma unroll
    for (int l = 0; l < 5; ++l) {
        float s = 0.f;
        #pragma unroll
        for (int k = 0; k < 9; ++k) s += g[k] * w_ce[l * 9 + k];
        s = s * bng[c] + bnb[c];
        t[l] = s > 0.f ? s : 0.f;
    }
    float att[9];
    #pragma unroll
    for (int k = 0; k < 9; ++k) {
        float s = 0.f;
        #pragma unroll
        for (int l = 0; l < 5; ++l) s += t[l] * w_gd[k * 5 + l];
        att[k] = 1.f / (1.f + expf(-s));
    }
    float kc0[9];
    float bk = b_kc[c];
    #pragma unroll
    for (int k = 0; k < 9; ++k) kc0[k] = bk;
    for (int c2 = 0; c2 < 128; ++c2) {
        float wv = w_kc[c * 128 + c2];
        #pragma unroll
        for (int k = 0; k < 9; ++k) kc0[k] += wv * py_s[c2][k];
    }
    #pragma unroll
    for (int k = 0; k < 9; ++k)
        kc[((long)n * 128 + c) * 9 + k] = kc0[k] * att[k];
}

// ---------------------------------------------------------------------------
// channel_after, NHWC form: reads cat_x (bf16 NHWC ch0..127 = x1), kc in regs,
// writes catfb ch0..127 (bf16 NHWC). Block = one row h; thread: 8 ch x 16 px.
// ---------------------------------------------------------------------------
__global__ __launch_bounds__(256) void channel_nhwc_kernel(
    const __hip_bfloat16* __restrict__ catx, const float* __restrict__ kc,
    __hip_bfloat16* __restrict__ catfb)
{
    const int h  = blockIdx.x;
    const int n  = blockIdx.y;
    const int cg = (threadIdx.x & 15) * 8;
    const int w0 = threadIdx.x >> 4;
    float k9[8][9];
    #pragma unroll
    for (int j = 0; j < 8; ++j)
        #pragma unroll
        for (int t = 0; t < 9; ++t) k9[j][t] = kc[((long)n * 128 + cg + j) * 9 + t];
    const long pbase = (long)n * HW;
    for (int it = 0; it < 6; ++it) {
        const int w = w0 + it * 16;
        float acc[8];
        #pragma unroll
        for (int j = 0; j < 8; ++j) acc[j] = 0.f;
        #pragma unroll
        for (int ky = 0; ky < 3; ++ky) {
            const int hh = h + ky - 1;
            if (hh < 0 || hh >= IMG) continue;
            #pragma unroll
            for (int kx = 0; kx < 3; ++kx) {
                const int ww = w + kx - 1;
                if (ww < 0 || ww >= IMG) continue;
                bf16x8 v = *reinterpret_cast<const bf16x8*>(
                    &catx[(pbase + hh * IMG + ww) * 256 + cg]);
                #pragma unroll
                for (int j = 0; j < 8; ++j)
                    acc[j] += k9[j][ky * 3 + kx] * (float)v[j];
            }
        }
        union { __hip_bfloat16 hh[8]; uint4 u; } pk;
        #pragma unroll
        for (int j = 0; j < 8; ++j) pk.hh[j] = __float2bfloat16(acc[j]);
        *reinterpret_cast<uint4*>(&catfb[(pbase + h * IMG + w) * 256 + cg]) = pk.u;
    }
}

// ---------------------------------------------------------------------------
// ks = 1x1 conv 128->9 on ksmid_bf [N][HW][128] bf16 (NHWC)
// ---------------------------------------------------------------------------
__global__ __launch_bounds__(256) void ks_nhwc_kernel(
    const __hip_bfloat16* __restrict__ ksmid, const float* __restrict__ w_ks2,
    const float* __restrict__ b_ks2, float* __restrict__ ks)
{
    __shared__ float w_s[9 * 128];
    const int tid = threadIdx.x;
    for (int i = tid; i < 1152; i += 256) w_s[i] = w_ks2[i];
    __syncthreads();
    const int p = blockIdx.x * 256 + tid;
    const int n = blockIdx.y;
    const __hip_bfloat16* row = ksmid + ((long)n * HW + p) * 128;
    float acc[9];
    #pragma unroll
    for (int k = 0; k < 9; ++k) acc[k] = b_ks2[k];
    #pragma unroll
    for (int vq = 0; vq < 16; ++vq) {
        bf16x8 v = *reinterpret_cast<const bf16x8*>(&row[vq * 8]);
        #pragma unroll
        for (int j = 0; j < 8; ++j) {
            float f = (float)v[j];
            #pragma unroll
            for (int k = 0; k < 9; ++k) acc[k] += w_s[k * 128 + vq * 8 + j] * f;
        }
    }
    #pragma unroll
    for (int k = 0; k < 9; ++k) ks[((long)n * 9 + k) * HW + p] = acc[k];
}

// ---------------------------------------------------------------------------
// ksp = conv3x3(x2, w_sp1, pad=1) -> 1 channel, NHWC data-parallel.
// ---------------------------------------------------------------------------
__global__ __launch_bounds__(256) void ksp_nhwc_kernel(
    const __hip_bfloat16* __restrict__ catx, const float* __restrict__ w_sp1,
    float* __restrict__ ksp)
{
    __shared__ float w_s[9][128];
    const int tid = threadIdx.x;
    for (int i = tid; i < 1152; i += 256) {
        int ci = i / 9, tap = i % 9;            // src layout [ci][tap]
        w_s[tap][ci] = w_sp1[i];
    }
    __syncthreads();
    const int p = blockIdx.x * 256 + tid;
    const int n = blockIdx.y;
    const int h = p / 96, w = p % 96;
    const long pbase = (long)n * HW;
    float acc = 0.f;
    #pragma unroll
    for (int ky = 0; ky < 3; ++ky) {
        const int hh = h + ky - 1;
        if (hh < 0 || hh >= IMG) continue;
        #pragma unroll
        for (int kx = 0; kx < 3; ++kx) {
            const int ww = w + kx - 1;
            if (ww < 0 || ww >= IMG) continue;
            const int tap = ky * 3 + kx;
            const __hip_bfloat16* row = &catx[(pbase + hh * IMG + ww) * 256 + 128];
            #pragma unroll
            for (int vq = 0; vq < 16; ++vq) {
                bf16x8 v = *reinterpret_cast<const bf16x8*>(&row[vq * 8]);
                #pragma unroll
                for (int j = 0; j < 8; ++j)
                    acc += w_s[tap][vq * 8 + j] * (float)v[j];
            }
        }
    }
    ksp[pbase + p] = acc;
}

// ---------------------------------------------------------------------------
__global__ __launch_bounds__(256) void sp_kernel(
    const float* __restrict__ ksp, const float* __restrict__ w_sp,
    float* __restrict__ sp)
{
    const int p = blockIdx.x * 256 + threadIdx.x;
    const int n = blockIdx.y;
    const int h = p / 96, w = p % 96;
    const float* kp = ksp + (long)n * HW;
    float acc = 0.f;
    #pragma unroll
    for (int dy = 0; dy < 3; ++dy)
        #pragma unroll
        for (int dx = 0; dx < 3; ++dx) {
            int hh = h + dy - 1, ww = w + dx - 1;
            if (hh < 0 || hh >= 96 || ww < 0 || ww >= 96) continue;
            float s = 0.f, m = -1e30f;
            #pragma unroll
            for (int iy = 0; iy < 3; ++iy)
                #pragma unroll
                for (int ix = 0; ix < 3; ++ix) {
                    int h2 = hh + iy - 1, w2 = ww + ix - 1;
                    float v = (h2 >= 0 && h2 < 96 && w2 >= 0 && w2 < 96) ? kp[h2 * 96 + w2] : 0.f;
                    s += v; m = fmaxf(m, v);
                }
            acc += w_sp[dy * 3 + dx] * (s * (1.f / 9.f)) + w_sp[9 + dy * 3 + dx] * m;
        }
    sp[(long)n * HW + p] = 1.f / (1.f + expf(-acc));
}

// ---------------------------------------------------------------------------
// spatial_after -> catfb ch128..255 (raw-reshape gather; cc = p/72)
// ---------------------------------------------------------------------------
__global__ __launch_bounds__(256) void spatial_kernel(
    const float* __restrict__ xd, const float* __restrict__ ks,
    const float* __restrict__ sp, __hip_bfloat16* __restrict__ catfb)
{
    const int cc = blockIdx.x;
    const int n  = blockIdx.y;
    const int tid = threadIdx.x;
    __shared__ float plane[HW];
    const float* src = xd + ((long)n * 256 + 128 + cc) * HW;
    for (int i = tid; i < HW / 4; i += 256)
        *reinterpret_cast<float4*>(&plane[i * 4]) = *reinterpret_cast<const float4*>(&src[i * 4]);
    __syncthreads();
    const int c  = tid & 127;
    const int pr = tid >> 7;
    const int c9 = c * 9;
    for (int j = 0; j < 36; ++j) {
        const int pl = pr + j * 2;
        const int p  = cc * 72 + pl;
        float spv = sp[(long)n * HW + p];
        float kv[9];
        #pragma unroll
        for (int k = 0; k < 9; ++k) kv[k] = ks[((long)n * 9 + k) * HW + p] * spv;
        const int base = pl * 1152 + c9;
        int kk0 = base / 9216;
        int r20 = base - kk0 * 9216;
        int h20 = r20 / 96;
        int w20 = r20 - h20 * 96;
        float acc = 0.f;
        #pragma unroll
        for (int k = 0; k < 9; ++k) {
            int kk = kk0, h2 = h20, w2 = w20 + k;
            if (w2 >= 96) { h2 += 1; w2 -= 96; }
            if (h2 >= 96) { kk += 1; h2 -= 96; }
            int hh = h2 + kk / 3 - 1;
            int ww = w2 + kk % 3 - 1;
            float v = (hh >= 0 && hh < 96 && ww >= 0 && ww < 96) ? plane[hh * 96 + ww] : 0.f;
            acc += v * kv[k];
        }
        catfb[((long)n * HW + p) * 256 + 128 + c] = __float2bfloat16(acc);
    }
}

// ---------------------------------------------------------------------------
extern "C" void kernel_launch(void* const* d_in, const int* in_sizes, int n_in,
                              void* d_out, int out_size, void* d_ws, size_t ws_size,
                              hipStream_t stream)
{
    const float* x      = (const float*)d_in[0];
    const float* y      = (const float*)d_in[1];
    const float* w_down = (const float*)d_in[2];
    const float* b_down = (const float*)d_in[3];
    const float* w_ce   = (const float*)d_in[4];
    const float* w_gd   = (const float*)d_in[5];
    const float* bn_g   = (const float*)d_in[6];
    const float* bn_b   = (const float*)d_in[7];
    const float* w_kc   = (const float*)d_in[8];
    const float* b_kc   = (const float*)d_in[9];
    const float* w_ks1  = (const float*)d_in[10];
    const float* b_ks1  = (const float*)d_in[11];
    const float* w_ks2  = (const float*)d_in[12];
    const float* b_ks2  = (const float*)d_in[13];
    const float* w_sp1  = (const float*)d_in[14];
    const float* w_sp   = (const float*)d_in[15];
    const float* w_fb   = (const float*)d_in[16];
    const float* b_fb   = (const float*)d_in[17];
    const float* w_fuse = (const float*)d_in[18];
    const float* bn2_g  = (const float*)d_in[19];
    const float* bn2_b  = (const float*)d_in[20];
    const float* prelu  = (const float*)d_in[21];
    float* out = (float*)d_out;
    char* ws = (char*)d_ws;

    const long HWl = HW;
    // --- workspace layout ---
    float* xd = (float*)ws;                               ws += 8L * 256 * HWl * 4;  // 75.5MB
    // region2: 75.5MB. Timeline: x_t (whole) -> dead after conv1x1;
    //          then ksmid_bf (lower, bf16 NHWC) until ks; catfb (upper);
    //          finally cat_r1 (lower) written by fb conv.
    char* region2 = ws;                                   ws += 8L * HWl * 512 * 2;
    __hip_bfloat16* x_t      = (__hip_bfloat16*)region2;          // [N][HW][512] bf16
    __hip_bfloat16* cat_r1   = (__hip_bfloat16*)region2;          // [N][HW][256] bf16
    __hip_bfloat16* ksmid_bf = (__hip_bfloat16*)region2;          // [N][HW][128] bf16
    __hip_bfloat16* catfb    = (__hip_bfloat16*)(region2 + 8L * HWl * 256 * 2); // [N][HW][256]
    __hip_bfloat16* cat_x  = (__hip_bfloat16*)ws;         ws += 8L * HWl * 256 * 2;  // 37.7MB
    __hip_bfloat16* y2t    = (__hip_bfloat16*)ws;         ws += 8L * HWl * 128 * 2;  // 18.9MB
    __hip_bfloat16* wdown_bf = (__hip_bfloat16*)ws;       ws += 1L * 256 * 512 * 2;
    __hip_bfloat16* wks1_bf  = (__hip_bfloat16*)ws;       ws += 9L * 128 * 128 * 2;
    __hip_bfloat16* wfb_bf   = (__hip_bfloat16*)ws;       ws += 9L * 256 * 256 * 2;
    __hip_bfloat16* wfuse_bf = (__hip_bfloat16*)ws;       ws += 9L * 256 * 512 * 2;
    float* ks   = (float*)ws;  ws += 8L * 9 * HWl * 4;
    float* ksp  = (float*)ws;  ws += 8L * HWl * 4;
    float* spb  = (float*)ws;  ws += 8L * HWl * 4;
    float* gl   = (float*)ws;  ws += 8L * 128 * 9 * 4;
    float* py   = (float*)ws;  ws += 8L * 128 * 9 * 4;
    float* kc   = (float*)ws;  ws += 8L * 128 * 9 * 4;
    __hip_bfloat16* zp = (__hip_bfloat16*)ws;  ws += 256;

    (void)hipMemsetAsync((void*)zp, 0, 256, stream);

    // all weight conversions in one launch
    wconv_all_kernel<<<dim3(512, 4), 256, 0, stream>>>(
        w_down, w_ks1, w_fb, w_fuse, wdown_bf, wks1_bf, wfb_bf, wfuse_bf);

    // x -> NHWC bf16, then 1x1 down conv -> xd (fp32 NCHW) + cat_x (bf16 NHWC)
    nchw2nhwc_kernel<<<dim3(144, 16, 8), 256, 0, stream>>>(x, 512L * HWl, x_t, 512);
    mfma_conv<512, 1, false><<<dim3(12, 8, 8), 512, 102400, stream>>>(
        x_t, nullptr, wdown_bf, b_down, xd, 256L * HWl, cat_x, 256, 256,
        nullptr, nullptr, nullptr, zp);

    // y2 -> NHWC bf16
    nchw2nhwc_kernel<<<dim3(144, 4, 8), 256, 0, stream>>>(y + 128L * HWl, 256L * HWl, y2t, 128);

    // pools / attention
    pool_kernel<<<dim3(128, 8, 2), 256, 0, stream>>>(xd, y, gl, py);
    attkc_kernel<<<dim3(8), 128, 0, stream>>>(gl, py, w_ce, w_gd, bn_g, bn_b, w_kc, b_kc, kc);

    // ks_mid = conv3x3(y2) -> ksmid_bf (bf16 NHWC; x_t dead now)
    mfma_conv<128, 9, false><<<dim3(12, 4, 8), 512, 162304, stream>>>(
        y2t, nullptr, wks1_bf, b_ks1, nullptr, 0, ksmid_bf, 128, 128,
        nullptr, nullptr, nullptr, zp);
    ks_nhwc_kernel<<<dim3(36, 8), 256, 0, stream>>>(ksmid_bf, w_ks2, b_ks2, ks);

    // ksp / sp  (ksp NHWC data-parallel from cat_x ch128..255)
    ksp_nhwc_kernel<<<dim3(36, 8), 256, 0, stream>>>(cat_x, w_sp1, ksp);
    sp_kernel<<<dim3(36, 8), 256, 0, stream>>>(ksp, w_sp, spb);

    // spatial_after -> catfb ch128..255 ; channel_after -> catfb ch0..127
    spatial_kernel<<<dim3(128, 8), 256, 0, stream>>>(xd, ks, spb, catfb);
    channel_nhwc_kernel<<<dim3(96, 8), 256, 0, stream>>>(cat_x, kc, catfb);

    // r1 = conv3x3(catfb, w_fb)+b -> cat_r1 (bf16 NHWC; ksmid dead)
    mfma_conv<256, 9, false><<<dim3(12, 8, 8), 512, 162304, stream>>>(
        catfb, nullptr, wfb_bf, b_fb, nullptr, 0, cat_r1, 256, 256,
        nullptr, nullptr, nullptr, zp);

    // out = prelu(bn(conv3x3([cat_x | cat_r1], w_fuse)))
    mfma_conv<512, 9, true><<<dim3(12, 8, 8), 512, 162304, stream>>>(
        cat_x, cat_r1, wfuse_bf, nullptr, out, 256L * HWl, nullptr, 0, 256,
        bn2_g, bn2_b, prelu, zp);
}

// Round 15
// 653.721 us; speedup vs baseline: 1.0796x; 1.0133x over previous
//
#include <hip/hip_runtime.h>
#include <hip/hip_bf16.h>
#include <math.h>

#define HW 9216
#define IMG 96

typedef __bf16 bf16x8 __attribute__((ext_vector_type(8)));
typedef float  f32x4  __attribute__((ext_vector_type(4)));

__device__ __forceinline__ void gload16(const void* g, void* l) {
    __builtin_amdgcn_global_load_lds((const unsigned int*)g, (unsigned int*)l, 16, 0, 0);
}

#define WAITVN(N) asm volatile("s_waitcnt vmcnt(" #N ")" ::: "memory")
#define BARX()    { asm volatile("" ::: "memory"); __builtin_amdgcn_s_barrier(); asm volatile("" ::: "memory"); }

// ---------------------------------------------------------------------------
// NCHW fp32 -> NHWC bf16 transpose/convert. grid (HW/64, cin/32, N)
// ---------------------------------------------------------------------------
__global__ __launch_bounds__(256) void nchw2nhwc_kernel(
    const float* __restrict__ src, long n_stride_src,
    __hip_bfloat16* __restrict__ dst, int dst_stride)
{
    __shared__ float tile[32][65];
    const int px0 = blockIdx.x * 64;
    const int c0  = blockIdx.y * 32;
    const int n   = blockIdx.z;
    const int tid = threadIdx.x;
    const int tx = tid & 63, ty = tid >> 6;
    #pragma unroll
    for (int i = 0; i < 8; ++i)
        tile[ty + i * 4][tx] = src[n * n_stride_src + (long)(c0 + ty + i * 4) * HW + px0 + tx];
    __syncthreads();
    const int ci = tid & 31, pxl = tid >> 5;
    #pragma unroll
    for (int j = 0; j < 8; ++j) {
        int px = pxl + j * 8;
        dst[((long)n * HW + px0 + px) * dst_stride + c0 + ci] = __float2bfloat16(tile[ci][px]);
    }
}

// ---------------------------------------------------------------------------
// all four weight conversions in ONE launch: dst[t][co][ci] = bf16(src[co][ci][t])
// ---------------------------------------------------------------------------
__global__ __launch_bounds__(256) void wconv_all_kernel(
    const float* __restrict__ w_down, const float* __restrict__ w_ks1,
    const float* __restrict__ w_fb,   const float* __restrict__ w_fuse,
    __hip_bfloat16* __restrict__ d_down, __hip_bfloat16* __restrict__ d_ks1,
    __hip_bfloat16* __restrict__ d_fb,   __hip_bfloat16* __restrict__ d_fuse)
{
    const float* src; __hip_bfloat16* dst; int cout, cin, taps;
    switch (blockIdx.y) {
        case 0:  src = w_down; dst = d_down; cout = 256; cin = 512; taps = 1; break;
        case 1:  src = w_ks1;  dst = d_ks1;  cout = 128; cin = 128; taps = 9; break;
        case 2:  src = w_fb;   dst = d_fb;   cout = 256; cin = 256; taps = 9; break;
        default: src = w_fuse; dst = d_fuse; cout = 256; cin = 512; taps = 9; break;
    }
    int idx = blockIdx.x * 256 + threadIdx.x;
    if (idx >= cout * cin) return;
    int co = idx / cin, ci = idx % cin;
    for (int t = 0; t < taps; ++t)
        dst[((long)t * cout + co) * cin + ci] = __float2bfloat16(src[(long)idx * taps + t]);
}

// ---------------------------------------------------------------------------
// MFMA implicit-GEMM conv (TAPS=9: 3x3 pad=1; TAPS=1: 1x1), bf16 in, fp32 acc.
// R10-proven geometry: 512 threads = 8 waves; tile co=32 x rows=8 x cols=96;
// ci-chunk 32; mfma 16x16x32. LDS: input dbuf (10x98 rows) + weight dbuf
// ([9][32][32]) = 162,304 B -> 1 block/CU, 2 waves/SIMD. Counted per-wave
// vmcnt keeps next-chunk stage in flight across the barrier.
// NCHW output only for co >= nchw_co0 (written at co - nchw_co0).
// SPLIT: ptr fixup at chunk 7->8 staging, dAB = (B - A) - 448.
// ---------------------------------------------------------------------------
template<int CIN, int TAPS, bool SPLIT>
__global__ __launch_bounds__(512, 1) void mfma_conv(
    const __hip_bfloat16* __restrict__ in_a,
    const __hip_bfloat16* __restrict__ in_b,
    const __hip_bfloat16* __restrict__ w_t,
    const float* __restrict__ bias,
    float* __restrict__ out_nchw, long nchw_nstride, int nchw_co0,
    __hip_bfloat16* __restrict__ out_nhwc, int nhwc_stride,
    int cout,
    const float* __restrict__ bng, const float* __restrict__ bnb,
    const float* __restrict__ pra,
    const __hip_bfloat16* __restrict__ zeropage)
{
    constexpr int ROWS = (TAPS == 9) ? 10 : 8;      // staged rows
    constexpr int COLS = (TAPS == 9) ? 98 : 96;
    constexpr int HOFF = (TAPS == 9) ? 1 : 0;
    constexpr int PSTR = SPLIT ? 256 : CIN;
    constexpr int NSEG_IN = ROWS * COLS * 4;        // 3920 / 3072
    constexpr int NSEG_W  = TAPS * 32 * 4;          // 1152 / 128
    constexpr int IN_BYTES = NSEG_IN * 16;          // 62720 / 49152
    constexpr int BUF = IN_BYTES + NSEG_W * 16;     // 81152 / 51200
    constexpr int NCHUNK = CIN / 32;
    constexpr int FULL_IN = NSEG_IN / 512;          // 7 / 6
    constexpr int IN_TAIL = NSEG_IN % 512;          // 336 / 0
    constexpr int FULL_W  = NSEG_W / 512;           // 2 / 0
    constexpr int W_TAIL  = NSEG_W % 512;           // 128 / 128
    constexpr int IT_IN = FULL_IN + (IN_TAIL ? 1 : 0);
    constexpr int IT_W  = FULL_W + (W_TAIL ? 1 : 0);

    extern __shared__ __align__(16) char lds[];     // 2*BUF

    const int h0   = blockIdx.x * 8;
    const int cob  = blockIdx.y * 32;
    const int n    = blockIdx.z;
    const int tid  = threadIdx.x;
    const int lane = tid & 63;
    const int wave = tid >> 6;
    const int l16  = lane & 15, lg = lane >> 4;

    const long dAB = SPLIT ? ((const char*)in_b - (const char*)in_a - 448) : 0;

    // ---- input staging pointers (advance 64B per ci-chunk) ----
    const char* inptr[IT_IN];
    int inval[IT_IN];
    #pragma unroll
    for (int t = 0; t < IT_IN; ++t) {
        int seg = tid + t * 512;
        int s2 = (seg < NSEG_IN) ? seg : 0;
        int pix = s2 >> 2, qp = s2 & 3;
        int r = pix / COLS, c = pix % COLS;
        int h = h0 + r - HOFF, w = c - HOFF;
        int q = qp ^ ((c >> 1) & 3);                 // inverse-swizzled source slot
        bool valid = (h >= 0 && h < IMG && w >= 0 && w < IMG);
        inptr[t] = valid
            ? (const char*)(in_a + ((long)n * HW + h * IMG + w) * PSTR + q * 8)
            : (const char*)zeropage;
        inval[t] = valid ? 1 : 0;
    }
    // ---- weight staging pointers ----
    const char* wptr[IT_W];
    #pragma unroll
    for (int t = 0; t < IT_W; ++t) {
        int seg = tid + t * 512;
        int s2 = (seg < NSEG_W) ? seg : 0;
        int tap = s2 >> 7, rem = s2 & 127;
        int co = rem >> 2, qp = rem & 3;
        int q = qp ^ ((co >> 1) & 3);
        wptr[t] = (const char*)(w_t + ((long)tap * cout + cob + co) * CIN + q * 8);
    }

    auto stage = [&](int bb, long adv) {
        char* ib = lds + bb * BUF;
        char* wb = ib + IN_BYTES;
        #pragma unroll
        for (int t = 0; t < FULL_IN; ++t) {
            gload16(inptr[t], ib + (tid + t * 512) * 16);
            if (inval[t]) inptr[t] += adv;
        }
        if (IN_TAIL) {
            if (tid < IN_TAIL) {
                gload16(inptr[IT_IN - 1], ib + (tid + FULL_IN * 512) * 16);
                if (inval[IT_IN - 1]) inptr[IT_IN - 1] += adv;
            }
        }
        #pragma unroll
        for (int t = 0; t < FULL_W; ++t) {
            gload16(wptr[t], wb + (tid + t * 512) * 16);
            wptr[t] += 64;
        }
        if (W_TAIL) {
            if (tid < W_TAIL) {
                gload16(wptr[IT_W - 1], wb + (tid + FULL_W * 512) * 16);
                wptr[IT_W - 1] += 64;
            }
        }
    };

    f32x4 acc[2][6];
    #pragma unroll
    for (int m = 0; m < 2; ++m)
        #pragma unroll
        for (int nf = 0; nf < 6; ++nf) acc[m][nf] = (f32x4){0.f, 0.f, 0.f, 0.f};

    const int qa = lg ^ ((l16 >> 1) & 3);
    const int a_off = l16 * 64 + qa * 16;

    stage(0, 64);
    WAITVN(0); BARX();

    for (int ch = 0; ch < NCHUNK; ++ch) {
        if (ch + 1 < NCHUNK) {
            long adv = (SPLIT && (ch + 1) == 7) ? dAB : 64;
            stage((ch + 1) & 1, adv);
            // per-wave count of loads just issued -> previous stage drained,
            // new stage stays in flight across the barrier
            if constexpr (TAPS == 9) {
                if (wave < 2) { WAITVN(11); } else if (wave < 6) { WAITVN(10); } else { WAITVN(9); }
            } else {
                if (wave < 2) { WAITVN(7); } else { WAITVN(6); }
            }
        } else {
            WAITVN(0);
        }
        BARX();

        const char* ib = lds + (ch & 1) * BUF;
        const char* wb = ib + IN_BYTES;
        __builtin_amdgcn_s_setprio(1);
        #pragma unroll
        for (int tap = 0; tap < TAPS; ++tap) {
            const int g = (TAPS == 9) ? tap / 3 : 0;
            const int kx = (TAPS == 9) ? tap % 3 : 0;
            bf16x8 a0 = *(const bf16x8*)(wb + tap * 2048 + a_off);
            bf16x8 a1 = *(const bf16x8*)(wb + tap * 2048 + 1024 + a_off);
            #pragma unroll
            for (int nf = 0; nf < 6; ++nf) {
                const int c = nf * 16 + l16 + kx;
                const int qb = lg ^ ((c >> 1) & 3);
                bf16x8 b = *(const bf16x8*)(ib + ((wave + g) * COLS + c) * 64 + qb * 16);
                acc[0][nf] = __builtin_amdgcn_mfma_f32_16x16x32_bf16(a0, b, acc[0][nf], 0, 0, 0);
                acc[1][nf] = __builtin_amdgcn_mfma_f32_16x16x32_bf16(a1, b, acc[1][nf], 0, 0, 0);
            }
        }
        __builtin_amdgcn_s_setprio(0);
        BARX();
    }

    // ---- epilogue ----
    const int hrow = h0 + wave;
    #pragma unroll
    for (int m = 0; m < 2; ++m) {
        const int co = cob + m * 16 + lg * 4;
        float bs[4], g4[4], b4[4], p4[4];
        #pragma unroll
        for (int r = 0; r < 4; ++r) bs[r] = bias ? bias[co + r] : 0.f;
        if (bng) {
            #pragma unroll
            for (int r = 0; r < 4; ++r) { g4[r] = bng[co + r]; b4[r] = bnb[co + r]; p4[r] = pra[co + r]; }
        }
        #pragma unroll
        for (int nf = 0; nf < 6; ++nf) {
            const int wcol = nf * 16 + l16;
            const long px = (long)hrow * IMG + wcol;
            float v[4];
            #pragma unroll
            for (int r = 0; r < 4; ++r) {
                v[r] = acc[m][nf][r] + bs[r];
                if (bng) {
                    v[r] = v[r] * g4[r] + b4[r];
                    v[r] = (v[r] >= 0.f) ? v[r] : p4[r] * v[r];
                }
            }
            if (out_nchw && co >= nchw_co0) {
                #pragma unroll
                for (int r = 0; r < 4; ++r)
                    out_nchw[(long)n * nchw_nstride + (long)(co - nchw_co0 + r) * HW + px] = v[r];
            }
            if (out_nhwc) {
                union { __hip_bfloat16 h[4]; uint2 u; } pk;
                #pragma unroll
                for (int r = 0; r < 4; ++r) pk.h[r] = __float2bfloat16(v[r]);
                *reinterpret_cast<uint2*>(&out_nhwc[((long)n * HW + px) * nhwc_stride + co]) = pk.u;
            }
        }
    }
}

// ---------------------------------------------------------------------------
// pool_to_3x3 for x1 from cat_x (bf16 NHWC ch0..127). grid (9 bins, N).
// 256 thr: cg = t&15 (8ch each), pxl = t>>4 (16 pixel lanes); LDS tree-reduce.
// ---------------------------------------------------------------------------
__global__ __launch_bounds__(256) void pool_x_nhwc_kernel(
    const __hip_bfloat16* __restrict__ catx, float* __restrict__ gl)
{
    const int bin = blockIdx.x;
    const int n   = blockIdx.y;
    const int bh = bin / 3, bw = bin % 3;
    const int tid = threadIdx.x;
    const int cg  = tid & 15;      // channel group (8 ch)
    const int pxl = tid >> 4;      // pixel lane (16)
    const long pbase = (long)n * HW;
    float acc[8];
    #pragma unroll
    for (int j = 0; j < 8; ++j) acc[j] = 0.f;
    for (int it = 0; it < 64; ++it) {
        const int i = pxl + it * 16;           // 0..1023
        const int h = bh * 32 + (i >> 5);
        const int w = bw * 32 + (i & 31);
        bf16x8 v = *reinterpret_cast<const bf16x8*>(&catx[(pbase + h * IMG + w) * 256 + cg * 8]);
        #pragma unroll
        for (int j = 0; j < 8; ++j) acc[j] += (float)v[j];
    }
    __shared__ float red[16][16][8];
    #pragma unroll
    for (int j = 0; j < 8; ++j) red[pxl][cg][j] = acc[j];
    __syncthreads();
    // reduce over pxl (16) with 128 threads: thread t<128: cg2 = t&15, j = t>>4
    if (tid < 128) {
        const int cg2 = tid & 15, j = tid >> 4;
        float s = 0.f;
        #pragma unroll
        for (int p = 0; p < 16; ++p) s += red[p][cg2][j];
        gl[((long)n * 128 + cg2 * 8 + j) * 9 + bin] = s * (1.f / 1024.f);
    }
}

// ---------------------------------------------------------------------------
// pool_to_3x3 for y1 (y ch 0..127, fp32 NCHW). grid (128, N).
// ---------------------------------------------------------------------------
__global__ __launch_bounds__(256) void pool_y_kernel(
    const float* __restrict__ y, float* __restrict__ py)
{
    const int c = blockIdx.x, n = blockIdx.y;
    const int tid = threadIdx.x;
    const float* src = y + ((long)n * 256 + c) * HW;
    float local[9];
    #pragma unroll
    for (int k = 0; k < 9; ++k) local[k] = 0.f;
    for (int i = tid; i < HW; i += 256) {
        int h = i / 96, w = i % 96;
        local[(h / 32) * 3 + (w / 32)] += src[i];
    }
    __shared__ float red[9][4];
    const int wv = tid >> 6, lane = tid & 63;
    #pragma unroll
    for (int k = 0; k < 9; ++k) {
        float v = local[k];
        for (int off = 32; off > 0; off >>= 1) v += __shfl_down(v, off, 64);
        if (lane == 0) red[k][wv] = v;
    }
    __syncthreads();
    if (tid < 9) {
        float s = (red[tid][0] + red[tid][1] + red[tid][2] + red[tid][3]) * (1.f / 1024.f);
        py[((long)n * 128 + c) * 9 + tid] = s;
    }
}

// ---------------------------------------------------------------------------
__global__ __launch_bounds__(128) void attkc_kernel(
    const float* __restrict__ gl, const float* __restrict__ py,
    const float* __restrict__ w_ce, const float* __restrict__ w_gd,
    const float* __restrict__ bng, const float* __restrict__ bnb,
    const float* __restrict__ w_kc, const float* __restrict__ b_kc,
    float* __restrict__ kc)
{
    const int n = blockIdx.x, c = threadIdx.x;
    __shared__ float py_s[128][9];
    #pragma unroll
    for (int k = 0; k < 9; ++k) py_s[c][k] = py[((long)n * 128 + c) * 9 + k];
    __syncthreads();
    float g[9];
    #pragma unroll
    for (int k = 0; k < 9; ++k) g[k] = gl[((long)n * 128 + c) * 9 + k];
    float t[5];
    #pragma unroll
    for (int l = 0; l < 5; ++l) {
        float s = 0.f;
        #pragma unroll
        for (int k = 0; k < 9; ++k) s += g[k] * w_ce[l * 9 + k];
        s = s * bng[c] + bnb[c];
        t[l] = s > 0.f ? s : 0.f;
    }
    float att[9];
    #pragma unroll
    for (int k = 0; k < 9; ++k) {
        float s = 0.f;
        #pragma unroll
        for (int l = 0; l < 5; ++l) s += t[l] * w_gd[k * 5 + l];
        att[k] = 1.f / (1.f + expf(-s));
    }
    float kc0[9];
    float bk = b_kc[c];
    #pragma unroll
    for (int k = 0; k < 9; ++k) kc0[k] = bk;
    for (int c2 = 0; c2 < 128; ++c2) {
        float wv = w_kc[c * 128 + c2];
        #pragma unroll
        for (int k = 0; k < 9; ++k) kc0[k] += wv * py_s[c2][k];
    }
    #pragma unroll
    for (int k = 0; k < 9; ++k)
        kc[((long)n * 128 + c) * 9 + k] = kc0[k] * att[k];
}

// ---------------------------------------------------------------------------
// channel_after, NHWC form: reads cat_x (bf16 NHWC ch0..127 = x1), kc in regs,
// writes catfb ch0..127 (bf16 NHWC). Block = one row h; thread: 8 ch x 16 px.
// ---------------------------------------------------------------------------
__global__ __launch_bounds__(256) void channel_nhwc_kernel(
    const __hip_bfloat16* __restrict__ catx, const float* __restrict__ kc,
    __hip_bfloat16* __restrict__ catfb)
{
    const int h  = blockIdx.x;
    const int n  = blockIdx.y;
    const int cg = (threadIdx.x & 15) * 8;
    const int w0 = threadIdx.x >> 4;
    float k9[8][9];
    #pragma unroll
    for (int j = 0; j < 8; ++j)
        #pragma unroll
        for (int t = 0; t < 9; ++t) k9[j][t] = kc[((long)n * 128 + cg + j) * 9 + t];
    const long pbase = (long)n * HW;
    for (int it = 0; it < 6; ++it) {
        const int w = w0 + it * 16;
        float acc[8];
        #pragma unroll
        for (int j = 0; j < 8; ++j) acc[j] = 0.f;
        #pragma unroll
        for (int ky = 0; ky < 3; ++ky) {
            const int hh = h + ky - 1;
            if (hh < 0 || hh >= IMG) continue;
            #pragma unroll
            for (int kx = 0; kx < 3; ++kx) {
                const int ww = w + kx - 1;
                if (ww < 0 || ww >= IMG) continue;
                bf16x8 v = *reinterpret_cast<const bf16x8*>(
                    &catx[(pbase + hh * IMG + ww) * 256 + cg]);
                #pragma unroll
                for (int j = 0; j < 8; ++j)
                    acc[j] += k9[j][ky * 3 + kx] * (float)v[j];
            }
        }
        union { __hip_bfloat16 hh[8]; uint4 u; } pk;
        #pragma unroll
        for (int j = 0; j < 8; ++j) pk.hh[j] = __float2bfloat16(acc[j]);
        *reinterpret_cast<uint4*>(&catfb[(pbase + h * IMG + w) * 256 + cg]) = pk.u;
    }
}

// ---------------------------------------------------------------------------
// ks = 1x1 conv 128->9 on ksmid_bf [N][HW][128] bf16 (NHWC)
// ---------------------------------------------------------------------------
__global__ __launch_bounds__(256) void ks_nhwc_kernel(
    const __hip_bfloat16* __restrict__ ksmid, const float* __restrict__ w_ks2,
    const float* __restrict__ b_ks2, float* __restrict__ ks)
{
    __shared__ float w_s[9 * 128];
    const int tid = threadIdx.x;
    for (int i = tid; i < 1152; i += 256) w_s[i] = w_ks2[i];
    __syncthreads();
    const int p = blockIdx.x * 256 + tid;
    const int n = blockIdx.y;
    const __hip_bfloat16* row = ksmid + ((long)n * HW + p) * 128;
    float acc[9];
    #pragma unroll
    for (int k = 0; k < 9; ++k) acc[k] = b_ks2[k];
    #pragma unroll
    for (int vq = 0; vq < 16; ++vq) {
        bf16x8 v = *reinterpret_cast<const bf16x8*>(&row[vq * 8]);
        #pragma unroll
        for (int j = 0; j < 8; ++j) {
            float f = (float)v[j];
            #pragma unroll
            for (int k = 0; k < 9; ++k) acc[k] += w_s[k * 128 + vq * 8 + j] * f;
        }
    }
    #pragma unroll
    for (int k = 0; k < 9; ++k) ks[((long)n * 9 + k) * HW + p] = acc[k];
}

// ---------------------------------------------------------------------------
// ksp = conv3x3(x2, w_sp1, pad=1) -> 1 channel, NHWC data-parallel.
// ---------------------------------------------------------------------------
__global__ __launch_bounds__(256) void ksp_nhwc_kernel(
    const __hip_bfloat16* __restrict__ catx, const float* __restrict__ w_sp1,
    float* __restrict__ ksp)
{
    __shared__ float w_s[9][128];
    const int tid = threadIdx.x;
    for (int i = tid; i < 1152; i += 256) {
        int ci = i / 9, tap = i % 9;            // src layout [ci][tap]
        w_s[tap][ci] = w_sp1[i];
    }
    __syncthreads();
    const int p = blockIdx.x * 256 + tid;
    const int n = blockIdx.y;
    const int h = p / 96, w = p % 96;
    const long pbase = (long)n * HW;
    float acc = 0.f;
    #pragma unroll
    for (int ky = 0; ky < 3; ++ky) {
        const int hh = h + ky - 1;
        if (hh < 0 || hh >= IMG) continue;
        #pragma unroll
        for (int kx = 0; kx < 3; ++kx) {
            const int ww = w + kx - 1;
            if (ww < 0 || ww >= IMG) continue;
            const int tap = ky * 3 + kx;
            const __hip_bfloat16* row = &catx[(pbase + hh * IMG + ww) * 256 + 128];
            #pragma unroll
            for (int vq = 0; vq < 16; ++vq) {
                bf16x8 v = *reinterpret_cast<const bf16x8*>(&row[vq * 8]);
                #pragma unroll
                for (int j = 0; j < 8; ++j)
                    acc += w_s[tap][vq * 8 + j] * (float)v[j];
            }
        }
    }
    ksp[pbase + p] = acc;
}

// ---------------------------------------------------------------------------
__global__ __launch_bounds__(256) void sp_kernel(
    const float* __restrict__ ksp, const float* __restrict__ w_sp,
    float* __restrict__ sp)
{
    const int p = blockIdx.x * 256 + threadIdx.x;
    const int n = blockIdx.y;
    const int h = p / 96, w = p % 96;
    const float* kp = ksp + (long)n * HW;
    float acc = 0.f;
    #pragma unroll
    for (int dy = 0; dy < 3; ++dy)
        #pragma unroll
        for (int dx = 0; dx < 3; ++dx) {
            int hh = h + dy - 1, ww = w + dx - 1;
            if (hh < 0 || hh >= 96 || ww < 0 || ww >= 96) continue;
            float s = 0.f, m = -1e30f;
            #pragma unroll
            for (int iy = 0; iy < 3; ++iy)
                #pragma unroll
                for (int ix = 0; ix < 3; ++ix) {
                    int h2 = hh + iy - 1, w2 = ww + ix - 1;
                    float v = (h2 >= 0 && h2 < 96 && w2 >= 0 && w2 < 96) ? kp[h2 * 96 + w2] : 0.f;
                    s += v; m = fmaxf(m, v);
                }
            acc += w_sp[dy * 3 + dx] * (s * (1.f / 9.f)) + w_sp[9 + dy * 3 + dx] * m;
        }
    sp[(long)n * HW + p] = 1.f / (1.f + expf(-acc));
}

// ---------------------------------------------------------------------------
// spatial_after -> catfb ch128..255 (raw-reshape gather; cc = p/72)
// xd now holds ONLY x2 ([N][128][HW] fp32).
// ---------------------------------------------------------------------------
__global__ __launch_bounds__(256) void spatial_kernel(
    const float* __restrict__ xd, const float* __restrict__ ks,
    const float* __restrict__ sp, __hip_bfloat16* __restrict__ catfb)
{
    const int cc = blockIdx.x;
    const int n  = blockIdx.y;
    const int tid = threadIdx.x;
    __shared__ float plane[HW];
    const float* src = xd + ((long)n * 128 + cc) * HW;
    for (int i = tid; i < HW / 4; i += 256)
        *reinterpret_cast<float4*>(&plane[i * 4]) = *reinterpret_cast<const float4*>(&src[i * 4]);
    __syncthreads();
    const int c  = tid & 127;
    const int pr = tid >> 7;
    const int c9 = c * 9;
    for (int j = 0; j < 36; ++j) {
        const int pl = pr + j * 2;
        const int p  = cc * 72 + pl;
        float spv = sp[(long)n * HW + p];
        float kv[9];
        #pragma unroll
        for (int k = 0; k < 9; ++k) kv[k] = ks[((long)n * 9 + k) * HW + p] * spv;
        const int base = pl * 1152 + c9;
        int kk0 = base / 9216;
        int r20 = base - kk0 * 9216;
        int h20 = r20 / 96;
        int w20 = r20 - h20 * 96;
        float acc = 0.f;
        #pragma unroll
        for (int k = 0; k < 9; ++k) {
            int kk = kk0, h2 = h20, w2 = w20 + k;
            if (w2 >= 96) { h2 += 1; w2 -= 96; }
            if (h2 >= 96) { kk += 1; h2 -= 96; }
            int hh = h2 + kk / 3 - 1;
            int ww = w2 + kk % 3 - 1;
            float v = (hh >= 0 && hh < 96 && ww >= 0 && ww < 96) ? plane[hh * 96 + ww] : 0.f;
            acc += v * kv[k];
        }
        catfb[((long)n * HW + p) * 256 + 128 + c] = __float2bfloat16(acc);
    }
}

// ---------------------------------------------------------------------------
extern "C" void kernel_launch(void* const* d_in, const int* in_sizes, int n_in,
                              void* d_out, int out_size, void* d_ws, size_t ws_size,
                              hipStream_t stream)
{
    const float* x      = (const float*)d_in[0];
    const float* y      = (const float*)d_in[1];
    const float* w_down = (const float*)d_in[2];
    const float* b_down = (const float*)d_in[3];
    const float* w_ce   = (const float*)d_in[4];
    const float* w_gd   = (const float*)d_in[5];
    const float* bn_g   = (const float*)d_in[6];
    const float* bn_b   = (const float*)d_in[7];
    const float* w_kc   = (const float*)d_in[8];
    const float* b_kc   = (const float*)d_in[9];
    const float* w_ks1  = (const float*)d_in[10];
    const float* b_ks1  = (const float*)d_in[11];
    const float* w_ks2  = (const float*)d_in[12];
    const float* b_ks2  = (const float*)d_in[13];
    const float* w_sp1  = (const float*)d_in[14];
    const float* w_sp   = (const float*)d_in[15];
    const float* w_fb   = (const float*)d_in[16];
    const float* b_fb   = (const float*)d_in[17];
    const float* w_fuse = (const float*)d_in[18];
    const float* bn2_g  = (const float*)d_in[19];
    const float* bn2_b  = (const float*)d_in[20];
    const float* prelu  = (const float*)d_in[21];
    float* out = (float*)d_out;
    char* ws = (char*)d_ws;

    const long HWl = HW;
    // --- workspace layout ---
    float* xd = (float*)ws;                               ws += 8L * 128 * HWl * 4;  // 37.7MB (x2 only)
    // region2: 75.5MB. Timeline: x_t (whole) -> dead after conv1x1;
    //          then ksmid_bf (lower, bf16 NHWC) until ks; catfb (upper);
    //          finally cat_r1 (lower) written by fb conv.
    char* region2 = ws;                                   ws += 8L * HWl * 512 * 2;
    __hip_bfloat16* x_t      = (__hip_bfloat16*)region2;          // [N][HW][512] bf16
    __hip_bfloat16* cat_r1   = (__hip_bfloat16*)region2;          // [N][HW][256] bf16
    __hip_bfloat16* ksmid_bf = (__hip_bfloat16*)region2;          // [N][HW][128] bf16
    __hip_bfloat16* catfb    = (__hip_bfloat16*)(region2 + 8L * HWl * 256 * 2); // [N][HW][256]
    __hip_bfloat16* cat_x  = (__hip_bfloat16*)ws;         ws += 8L * HWl * 256 * 2;  // 37.7MB
    __hip_bfloat16* y2t    = (__hip_bfloat16*)ws;         ws += 8L * HWl * 128 * 2;  // 18.9MB
    __hip_bfloat16* wdown_bf = (__hip_bfloat16*)ws;       ws += 1L * 256 * 512 * 2;
    __hip_bfloat16* wks1_bf  = (__hip_bfloat16*)ws;       ws += 9L * 128 * 128 * 2;
    __hip_bfloat16* wfb_bf   = (__hip_bfloat16*)ws;       ws += 9L * 256 * 256 * 2;
    __hip_bfloat16* wfuse_bf = (__hip_bfloat16*)ws;       ws += 9L * 256 * 512 * 2;
    float* ks   = (float*)ws;  ws += 8L * 9 * HWl * 4;
    float* ksp  = (float*)ws;  ws += 8L * HWl * 4;
    float* spb  = (float*)ws;  ws += 8L * HWl * 4;
    float* gl   = (float*)ws;  ws += 8L * 128 * 9 * 4;
    float* py   = (float*)ws;  ws += 8L * 128 * 9 * 4;
    float* kc   = (float*)ws;  ws += 8L * 128 * 9 * 4;
    __hip_bfloat16* zp = (__hip_bfloat16*)ws;  ws += 256;

    (void)hipMemsetAsync((void*)zp, 0, 256, stream);

    // all weight conversions in one launch
    wconv_all_kernel<<<dim3(512, 4), 256, 0, stream>>>(
        w_down, w_ks1, w_fb, w_fuse, wdown_bf, wks1_bf, wfb_bf, wfuse_bf);

    // x -> NHWC bf16, then 1x1 down conv -> xd (x2 only, fp32) + cat_x (bf16 NHWC)
    nchw2nhwc_kernel<<<dim3(144, 16, 8), 256, 0, stream>>>(x, 512L * HWl, x_t, 512);
    mfma_conv<512, 1, false><<<dim3(12, 8, 8), 512, 102400, stream>>>(
        x_t, nullptr, wdown_bf, b_down, xd, 128L * HWl, 128, cat_x, 256, 256,
        nullptr, nullptr, nullptr, zp);

    // y2 -> NHWC bf16
    nchw2nhwc_kernel<<<dim3(144, 4, 8), 256, 0, stream>>>(y + 128L * HWl, 256L * HWl, y2t, 128);

    // pools / attention
    pool_x_nhwc_kernel<<<dim3(9, 8), 256, 0, stream>>>(cat_x, gl);
    pool_y_kernel<<<dim3(128, 8), 256, 0, stream>>>(y, py);
    attkc_kernel<<<dim3(8), 128, 0, stream>>>(gl, py, w_ce, w_gd, bn_g, bn_b, w_kc, b_kc, kc);

    // ks_mid = conv3x3(y2) -> ksmid_bf (bf16 NHWC; x_t dead now)
    mfma_conv<128, 9, false><<<dim3(12, 4, 8), 512, 162304, stream>>>(
        y2t, nullptr, wks1_bf, b_ks1, nullptr, 0, 0, ksmid_bf, 128, 128,
        nullptr, nullptr, nullptr, zp);
    ks_nhwc_kernel<<<dim3(36, 8), 256, 0, stream>>>(ksmid_bf, w_ks2, b_ks2, ks);

    // ksp / sp  (ksp NHWC data-parallel from cat_x ch128..255)
    ksp_nhwc_kernel<<<dim3(36, 8), 256, 0, stream>>>(cat_x, w_sp1, ksp);
    sp_kernel<<<dim3(36, 8), 256, 0, stream>>>(ksp, w_sp, spb);

    // spatial_after -> catfb ch128..255 ; channel_after -> catfb ch0..127
    spatial_kernel<<<dim3(128, 8), 256, 0, stream>>>(xd, ks, spb, catfb);
    channel_nhwc_kernel<<<dim3(96, 8), 256, 0, stream>>>(cat_x, kc, catfb);

    // r1 = conv3x3(catfb, w_fb)+b -> cat_r1 (bf16 NHWC; ksmid dead)
    mfma_conv<256, 9, false><<<dim3(12, 8, 8), 512, 162304, stream>>>(
        catfb, nullptr, wfb_bf, b_fb, nullptr, 0, 0, cat_r1, 256, 256,
        nullptr, nullptr, nullptr, zp);

    // out = prelu(bn(conv3x3([cat_x | cat_r1], w_fuse)))
    mfma_conv<512, 9, true><<<dim3(12, 8, 8), 512, 162304, stream>>>(
        cat_x, cat_r1, wfuse_bf, nullptr, out, 256L * HWl, 0, nullptr, 0, 256,
        bn2_g, bn2_b, prelu, zp);
}

// Round 16
// 635.874 us; speedup vs baseline: 1.1099x; 1.0281x over previous
//
#include <hip/hip_runtime.h>
#include <hip/hip_bf16.h>
#include <math.h>

#define HW 9216
#define IMG 96

typedef __bf16 bf16x8 __attribute__((ext_vector_type(8)));
typedef float  f32x4  __attribute__((ext_vector_type(4)));

__device__ __forceinline__ void gload16(const void* g, void* l) {
    __builtin_amdgcn_global_load_lds((const unsigned int*)g, (unsigned int*)l, 16, 0, 0);
}

#define WAITVN(N) asm volatile("s_waitcnt vmcnt(" #N ")" ::: "memory")
#define BARX()    { asm volatile("" ::: "memory"); __builtin_amdgcn_s_barrier(); asm volatile("" ::: "memory"); }

// ---------------------------------------------------------------------------
// NCHW fp32 -> NHWC bf16 transpose/convert. grid (HW/64, cin/32, N)
// ---------------------------------------------------------------------------
__global__ __launch_bounds__(256) void nchw2nhwc_kernel(
    const float* __restrict__ src, long n_stride_src,
    __hip_bfloat16* __restrict__ dst, int dst_stride)
{
    __shared__ float tile[32][65];
    const int px0 = blockIdx.x * 64;
    const int c0  = blockIdx.y * 32;
    const int n   = blockIdx.z;
    const int tid = threadIdx.x;
    const int tx = tid & 63, ty = tid >> 6;
    #pragma unroll
    for (int i = 0; i < 8; ++i)
        tile[ty + i * 4][tx] = src[n * n_stride_src + (long)(c0 + ty + i * 4) * HW + px0 + tx];
    __syncthreads();
    const int ci = tid & 31, pxl = tid >> 5;
    #pragma unroll
    for (int j = 0; j < 8; ++j) {
        int px = pxl + j * 8;
        dst[((long)n * HW + px0 + px) * dst_stride + c0 + ci] = __float2bfloat16(tile[ci][px]);
    }
}

// ---------------------------------------------------------------------------
// all four weight conversions in ONE launch: dst[t][co][ci] = bf16(src[co][ci][t])
// ---------------------------------------------------------------------------
__global__ __launch_bounds__(256) void wconv_all_kernel(
    const float* __restrict__ w_down, const float* __restrict__ w_ks1,
    const float* __restrict__ w_fb,   const float* __restrict__ w_fuse,
    __hip_bfloat16* __restrict__ d_down, __hip_bfloat16* __restrict__ d_ks1,
    __hip_bfloat16* __restrict__ d_fb,   __hip_bfloat16* __restrict__ d_fuse)
{
    const float* src; __hip_bfloat16* dst; int cout, cin, taps;
    switch (blockIdx.y) {
        case 0:  src = w_down; dst = d_down; cout = 256; cin = 512; taps = 1; break;
        case 1:  src = w_ks1;  dst = d_ks1;  cout = 128; cin = 128; taps = 9; break;
        case 2:  src = w_fb;   dst = d_fb;   cout = 256; cin = 256; taps = 9; break;
        default: src = w_fuse; dst = d_fuse; cout = 256; cin = 512; taps = 9; break;
    }
    int idx = blockIdx.x * 256 + threadIdx.x;
    if (idx >= cout * cin) return;
    int co = idx / cin, ci = idx % cin;
    for (int t = 0; t < taps; ++t)
        dst[((long)t * cout + co) * cin + ci] = __float2bfloat16(src[(long)idx * taps + t]);
}

// ---------------------------------------------------------------------------
// MFMA implicit-GEMM conv (TAPS=9: 3x3 pad=1; TAPS=1: 1x1), bf16 in, fp32 acc.
// R10-proven geometry: 512 threads = 8 waves; tile co=32 x rows=8 x cols=96;
// ci-chunk 32; mfma 16x16x32. LDS 162,304 B -> 1 block/CU, 2 waves/SIMD.
// Counted per-wave vmcnt keeps next-chunk stage in flight across the barrier.
// T1 XCD SWIZZLE: 1D grid, decoded so the NY co-blocks sharing one input
// slab (same h-stripe, same n) land on ONE XCD under id%8 round-robin:
//   y = (id>>3) & (NY-1);  xz = (id&7) + 8*(id >> (3+NYL2));
// bijective (8*NY*12 = grid). Input slabs get NY-fold reuse in that XCD's L2.
// NCHW output only for co >= nchw_co0. SPLIT: dAB = (B - A) - 448 at ch 7->8.
// ---------------------------------------------------------------------------
template<int CIN, int TAPS, bool SPLIT, int NYL2>
__global__ __launch_bounds__(512, 1) void mfma_conv(
    const __hip_bfloat16* __restrict__ in_a,
    const __hip_bfloat16* __restrict__ in_b,
    const __hip_bfloat16* __restrict__ w_t,
    const float* __restrict__ bias,
    float* __restrict__ out_nchw, long nchw_nstride, int nchw_co0,
    __hip_bfloat16* __restrict__ out_nhwc, int nhwc_stride,
    int cout,
    const float* __restrict__ bng, const float* __restrict__ bnb,
    const float* __restrict__ pra,
    const __hip_bfloat16* __restrict__ zeropage)
{
    constexpr int ROWS = (TAPS == 9) ? 10 : 8;      // staged rows
    constexpr int COLS = (TAPS == 9) ? 98 : 96;
    constexpr int HOFF = (TAPS == 9) ? 1 : 0;
    constexpr int PSTR = SPLIT ? 256 : CIN;
    constexpr int NSEG_IN = ROWS * COLS * 4;        // 3920 / 3072
    constexpr int NSEG_W  = TAPS * 32 * 4;          // 1152 / 128
    constexpr int IN_BYTES = NSEG_IN * 16;          // 62720 / 49152
    constexpr int BUF = IN_BYTES + NSEG_W * 16;     // 81152 / 51200
    constexpr int NCHUNK = CIN / 32;
    constexpr int FULL_IN = NSEG_IN / 512;          // 7 / 6
    constexpr int IN_TAIL = NSEG_IN % 512;          // 336 / 0
    constexpr int FULL_W  = NSEG_W / 512;           // 2 / 0
    constexpr int W_TAIL  = NSEG_W % 512;           // 128 / 128
    constexpr int IT_IN = FULL_IN + (IN_TAIL ? 1 : 0);
    constexpr int IT_W  = FULL_W + (W_TAIL ? 1 : 0);

    extern __shared__ __align__(16) char lds[];     // 2*BUF

    // ---- XCD-aware decode of flat block id ----
    const int id  = blockIdx.x;
    const int yb  = (id >> 3) & ((1 << NYL2) - 1);
    const int xz  = (id & 7) + 8 * (id >> (3 + NYL2));
    const int h0  = (xz % 12) * 8;
    const int n   = xz / 12;
    const int cob = yb * 32;

    const int tid  = threadIdx.x;
    const int lane = tid & 63;
    const int wave = tid >> 6;
    const int l16  = lane & 15, lg = lane >> 4;

    const long dAB = SPLIT ? ((const char*)in_b - (const char*)in_a - 448) : 0;

    // ---- input staging pointers (advance 64B per ci-chunk) ----
    const char* inptr[IT_IN];
    int inval[IT_IN];
    #pragma unroll
    for (int t = 0; t < IT_IN; ++t) {
        int seg = tid + t * 512;
        int s2 = (seg < NSEG_IN) ? seg : 0;
        int pix = s2 >> 2, qp = s2 & 3;
        int r = pix / COLS, c = pix % COLS;
        int h = h0 + r - HOFF, w = c - HOFF;
        int q = qp ^ ((c >> 1) & 3);                 // inverse-swizzled source slot
        bool valid = (h >= 0 && h < IMG && w >= 0 && w < IMG);
        inptr[t] = valid
            ? (const char*)(in_a + ((long)n * HW + h * IMG + w) * PSTR + q * 8)
            : (const char*)zeropage;
        inval[t] = valid ? 1 : 0;
    }
    // ---- weight staging pointers ----
    const char* wptr[IT_W];
    #pragma unroll
    for (int t = 0; t < IT_W; ++t) {
        int seg = tid + t * 512;
        int s2 = (seg < NSEG_W) ? seg : 0;
        int tap = s2 >> 7, rem = s2 & 127;
        int co = rem >> 2, qp = rem & 3;
        int q = qp ^ ((co >> 1) & 3);
        wptr[t] = (const char*)(w_t + ((long)tap * cout + cob + co) * CIN + q * 8);
    }

    auto stage = [&](int bb, long adv) {
        char* ib = lds + bb * BUF;
        char* wb = ib + IN_BYTES;
        #pragma unroll
        for (int t = 0; t < FULL_IN; ++t) {
            gload16(inptr[t], ib + (tid + t * 512) * 16);
            if (inval[t]) inptr[t] += adv;
        }
        if (IN_TAIL) {
            if (tid < IN_TAIL) {
                gload16(inptr[IT_IN - 1], ib + (tid + FULL_IN * 512) * 16);
                if (inval[IT_IN - 1]) inptr[IT_IN - 1] += adv;
            }
        }
        #pragma unroll
        for (int t = 0; t < FULL_W; ++t) {
            gload16(wptr[t], wb + (tid + t * 512) * 16);
            wptr[t] += 64;
        }
        if (W_TAIL) {
            if (tid < W_TAIL) {
                gload16(wptr[IT_W - 1], wb + (tid + FULL_W * 512) * 16);
                wptr[IT_W - 1] += 64;
            }
        }
    };

    f32x4 acc[2][6];
    #pragma unroll
    for (int m = 0; m < 2; ++m)
        #pragma unroll
        for (int nf = 0; nf < 6; ++nf) acc[m][nf] = (f32x4){0.f, 0.f, 0.f, 0.f};

    const int qa = lg ^ ((l16 >> 1) & 3);
    const int a_off = l16 * 64 + qa * 16;

    stage(0, 64);
    WAITVN(0); BARX();

    for (int ch = 0; ch < NCHUNK; ++ch) {
        if (ch + 1 < NCHUNK) {
            long adv = (SPLIT && (ch + 1) == 7) ? dAB : 64;
            stage((ch + 1) & 1, adv);
            // per-wave count of loads just issued -> previous stage drained,
            // new stage stays in flight across the barrier
            if constexpr (TAPS == 9) {
                if (wave < 2) { WAITVN(11); } else if (wave < 6) { WAITVN(10); } else { WAITVN(9); }
            } else {
                if (wave < 2) { WAITVN(7); } else { WAITVN(6); }
            }
        } else {
            WAITVN(0);
        }
        BARX();

        const char* ib = lds + (ch & 1) * BUF;
        const char* wb = ib + IN_BYTES;
        __builtin_amdgcn_s_setprio(1);
        #pragma unroll
        for (int tap = 0; tap < TAPS; ++tap) {
            const int g = (TAPS == 9) ? tap / 3 : 0;
            const int kx = (TAPS == 9) ? tap % 3 : 0;
            bf16x8 a0 = *(const bf16x8*)(wb + tap * 2048 + a_off);
            bf16x8 a1 = *(const bf16x8*)(wb + tap * 2048 + 1024 + a_off);
            #pragma unroll
            for (int nf = 0; nf < 6; ++nf) {
                const int c = nf * 16 + l16 + kx;
                const int qb = lg ^ ((c >> 1) & 3);
                bf16x8 b = *(const bf16x8*)(ib + ((wave + g) * COLS + c) * 64 + qb * 16);
                acc[0][nf] = __builtin_amdgcn_mfma_f32_16x16x32_bf16(a0, b, acc[0][nf], 0, 0, 0);
                acc[1][nf] = __builtin_amdgcn_mfma_f32_16x16x32_bf16(a1, b, acc[1][nf], 0, 0, 0);
            }
        }
        __builtin_amdgcn_s_setprio(0);
        BARX();
    }

    // ---- epilogue ----
    const int hrow = h0 + wave;
    #pragma unroll
    for (int m = 0; m < 2; ++m) {
        const int co = cob + m * 16 + lg * 4;
        float bs[4], g4[4], b4[4], p4[4];
        #pragma unroll
        for (int r = 0; r < 4; ++r) bs[r] = bias ? bias[co + r] : 0.f;
        if (bng) {
            #pragma unroll
            for (int r = 0; r < 4; ++r) { g4[r] = bng[co + r]; b4[r] = bnb[co + r]; p4[r] = pra[co + r]; }
        }
        #pragma unroll
        for (int nf = 0; nf < 6; ++nf) {
            const int wcol = nf * 16 + l16;
            const long px = (long)hrow * IMG + wcol;
            float v[4];
            #pragma unroll
            for (int r = 0; r < 4; ++r) {
                v[r] = acc[m][nf][r] + bs[r];
                if (bng) {
                    v[r] = v[r] * g4[r] + b4[r];
                    v[r] = (v[r] >= 0.f) ? v[r] : p4[r] * v[r];
                }
            }
            if (out_nchw && co >= nchw_co0) {
                #pragma unroll
                for (int r = 0; r < 4; ++r)
                    out_nchw[(long)n * nchw_nstride + (long)(co - nchw_co0 + r) * HW + px] = v[r];
            }
            if (out_nhwc) {
                union { __hip_bfloat16 h[4]; uint2 u; } pk;
                #pragma unroll
                for (int r = 0; r < 4; ++r) pk.h[r] = __float2bfloat16(v[r]);
                *reinterpret_cast<uint2*>(&out_nhwc[((long)n * HW + px) * nhwc_stride + co]) = pk.u;
            }
        }
    }
}

// ---------------------------------------------------------------------------
// pool_to_3x3 for x1 from cat_x (bf16 NHWC ch0..127). grid (9 bins, N).
// ---------------------------------------------------------------------------
__global__ __launch_bounds__(256) void pool_x_nhwc_kernel(
    const __hip_bfloat16* __restrict__ catx, float* __restrict__ gl)
{
    const int bin = blockIdx.x;
    const int n   = blockIdx.y;
    const int bh = bin / 3, bw = bin % 3;
    const int tid = threadIdx.x;
    const int cg  = tid & 15;      // channel group (8 ch)
    const int pxl = tid >> 4;      // pixel lane (16)
    const long pbase = (long)n * HW;
    float acc[8];
    #pragma unroll
    for (int j = 0; j < 8; ++j) acc[j] = 0.f;
    for (int it = 0; it < 64; ++it) {
        const int i = pxl + it * 16;           // 0..1023
        const int h = bh * 32 + (i >> 5);
        const int w = bw * 32 + (i & 31);
        bf16x8 v = *reinterpret_cast<const bf16x8*>(&catx[(pbase + h * IMG + w) * 256 + cg * 8]);
        #pragma unroll
        for (int j = 0; j < 8; ++j) acc[j] += (float)v[j];
    }
    __shared__ float red[16][16][8];
    #pragma unroll
    for (int j = 0; j < 8; ++j) red[pxl][cg][j] = acc[j];
    __syncthreads();
    if (tid < 128) {
        const int cg2 = tid & 15, j = tid >> 4;
        float s = 0.f;
        #pragma unroll
        for (int p = 0; p < 16; ++p) s += red[p][cg2][j];
        gl[((long)n * 128 + cg2 * 8 + j) * 9 + bin] = s * (1.f / 1024.f);
    }
}

// ---------------------------------------------------------------------------
// pool_to_3x3 for y1 (y ch 0..127, fp32 NCHW). grid (128, N).
// ---------------------------------------------------------------------------
__global__ __launch_bounds__(256) void pool_y_kernel(
    const float* __restrict__ y, float* __restrict__ py)
{
    const int c = blockIdx.x, n = blockIdx.y;
    const int tid = threadIdx.x;
    const float* src = y + ((long)n * 256 + c) * HW;
    float local[9];
    #pragma unroll
    for (int k = 0; k < 9; ++k) local[k] = 0.f;
    for (int i = tid; i < HW; i += 256) {
        int h = i / 96, w = i % 96;
        local[(h / 32) * 3 + (w / 32)] += src[i];
    }
    __shared__ float red[9][4];
    const int wv = tid >> 6, lane = tid & 63;
    #pragma unroll
    for (int k = 0; k < 9; ++k) {
        float v = local[k];
        for (int off = 32; off > 0; off >>= 1) v += __shfl_down(v, off, 64);
        if (lane == 0) red[k][wv] = v;
    }
    __syncthreads();
    if (tid < 9) {
        float s = (red[tid][0] + red[tid][1] + red[tid][2] + red[tid][3]) * (1.f / 1024.f);
        py[((long)n * 128 + c) * 9 + tid] = s;
    }
}

// ---------------------------------------------------------------------------
__global__ __launch_bounds__(128) void attkc_kernel(
    const float* __restrict__ gl, const float* __restrict__ py,
    const float* __restrict__ w_ce, const float* __restrict__ w_gd,
    const float* __restrict__ bng, const float* __restrict__ bnb,
    const float* __restrict__ w_kc, const float* __restrict__ b_kc,
    float* __restrict__ kc)
{
    const int n = blockIdx.x, c = threadIdx.x;
    __shared__ float py_s[128][9];
    #pragma unroll
    for (int k = 0; k < 9; ++k) py_s[c][k] = py[((long)n * 128 + c) * 9 + k];
    __syncthreads();
    float g[9];
    #pragma unroll
    for (int k = 0; k < 9; ++k) g[k] = gl[((long)n * 128 + c) * 9 + k];
    float t[5];
    #pragma unroll
    for (int l = 0; l < 5; ++l) {
        float s = 0.f;
        #pragma unroll
        for (int k = 0; k < 9; ++k) s += g[k] * w_ce[l * 9 + k];
        s = s * bng[c] + bnb[c];
        t[l] = s > 0.f ? s : 0.f;
    }
    float att[9];
    #pragma unroll
    for (int k = 0; k < 9; ++k) {
        float s = 0.f;
        #pragma unroll
        for (int l = 0; l < 5; ++l) s += t[l] * w_gd[k * 5 + l];
        att[k] = 1.f / (1.f + expf(-s));
    }
    float kc0[9];
    float bk = b_kc[c];
    #pragma unroll
    for (int k = 0; k < 9; ++k) kc0[k] = bk;
    for (int c2 = 0; c2 < 128; ++c2) {
        float wv = w_kc[c * 128 + c2];
        #pragma unroll
        for (int k = 0; k < 9; ++k) kc0[k] += wv * py_s[c2][k];
    }
    #pragma unroll
    for (int k = 0; k < 9; ++k)
        kc[((long)n * 128 + c) * 9 + k] = kc0[k] * att[k];
}

// ---------------------------------------------------------------------------
// channel_after, NHWC form: reads cat_x (bf16 NHWC ch0..127 = x1), kc in regs,
// writes catfb ch0..127 (bf16 NHWC). Block = one row h; thread: 8 ch x 16 px.
// ---------------------------------------------------------------------------
__global__ __launch_bounds__(256) void channel_nhwc_kernel(
    const __hip_bfloat16* __restrict__ catx, const float* __restrict__ kc,
    __hip_bfloat16* __restrict__ catfb)
{
    const int h  = blockIdx.x;
    const int n  = blockIdx.y;
    const int cg = (threadIdx.x & 15) * 8;
    const int w0 = threadIdx.x >> 4;
    float k9[8][9];
    #pragma unroll
    for (int j = 0; j < 8; ++j)
        #pragma unroll
        for (int t = 0; t < 9; ++t) k9[j][t] = kc[((long)n * 128 + cg + j) * 9 + t];
    const long pbase = (long)n * HW;
    for (int it = 0; it < 6; ++it) {
        const int w = w0 + it * 16;
        float acc[8];
        #pragma unroll
        for (int j = 0; j < 8; ++j) acc[j] = 0.f;
        #pragma unroll
        for (int ky = 0; ky < 3; ++ky) {
            const int hh = h + ky - 1;
            if (hh < 0 || hh >= IMG) continue;
            #pragma unroll
            for (int kx = 0; kx < 3; ++kx) {
                const int ww = w + kx - 1;
                if (ww < 0 || ww >= IMG) continue;
                bf16x8 v = *reinterpret_cast<const bf16x8*>(
                    &catx[(pbase + hh * IMG + ww) * 256 + cg]);
                #pragma unroll
                for (int j = 0; j < 8; ++j)
                    acc[j] += k9[j][ky * 3 + kx] * (float)v[j];
            }
        }
        union { __hip_bfloat16 hh[8]; uint4 u; } pk;
        #pragma unroll
        for (int j = 0; j < 8; ++j) pk.hh[j] = __float2bfloat16(acc[j]);
        *reinterpret_cast<uint4*>(&catfb[(pbase + h * IMG + w) * 256 + cg]) = pk.u;
    }
}

// ---------------------------------------------------------------------------
// ks = 1x1 conv 128->9 on ksmid_bf [N][HW][128] bf16 (NHWC)
// ---------------------------------------------------------------------------
__global__ __launch_bounds__(256) void ks_nhwc_kernel(
    const __hip_bfloat16* __restrict__ ksmid, const float* __restrict__ w_ks2,
    const float* __restrict__ b_ks2, float* __restrict__ ks)
{
    __shared__ float w_s[9 * 128];
    const int tid = threadIdx.x;
    for (int i = tid; i < 1152; i += 256) w_s[i] = w_ks2[i];
    __syncthreads();
    const int p = blockIdx.x * 256 + tid;
    const int n = blockIdx.y;
    const __hip_bfloat16* row = ksmid + ((long)n * HW + p) * 128;
    float acc[9];
    #pragma unroll
    for (int k = 0; k < 9; ++k) acc[k] = b_ks2[k];
    #pragma unroll
    for (int vq = 0; vq < 16; ++vq) {
        bf16x8 v = *reinterpret_cast<const bf16x8*>(&row[vq * 8]);
        #pragma unroll
        for (int j = 0; j < 8; ++j) {
            float f = (float)v[j];
            #pragma unroll
            for (int k = 0; k < 9; ++k) acc[k] += w_s[k * 128 + vq * 8 + j] * f;
        }
    }
    #pragma unroll
    for (int k = 0; k < 9; ++k) ks[((long)n * 9 + k) * HW + p] = acc[k];
}

// ---------------------------------------------------------------------------
// ksp = conv3x3(x2, w_sp1, pad=1) -> 1 channel, NHWC data-parallel.
// ---------------------------------------------------------------------------
__global__ __launch_bounds__(256) void ksp_nhwc_kernel(
    const __hip_bfloat16* __restrict__ catx, const float* __restrict__ w_sp1,
    float* __restrict__ ksp)
{
    __shared__ float w_s[9][128];
    const int tid = threadIdx.x;
    for (int i = tid; i < 1152; i += 256) {
        int ci = i / 9, tap = i % 9;            // src layout [ci][tap]
        w_s[tap][ci] = w_sp1[i];
    }
    __syncthreads();
    const int p = blockIdx.x * 256 + tid;
    const int n = blockIdx.y;
    const int h = p / 96, w = p % 96;
    const long pbase = (long)n * HW;
    float acc = 0.f;
    #pragma unroll
    for (int ky = 0; ky < 3; ++ky) {
        const int hh = h + ky - 1;
        if (hh < 0 || hh >= IMG) continue;
        #pragma unroll
        for (int kx = 0; kx < 3; ++kx) {
            const int ww = w + kx - 1;
            if (ww < 0 || ww >= IMG) continue;
            const int tap = ky * 3 + kx;
            const __hip_bfloat16* row = &catx[(pbase + hh * IMG + ww) * 256 + 128];
            #pragma unroll
            for (int vq = 0; vq < 16; ++vq) {
                bf16x8 v = *reinterpret_cast<const bf16x8*>(&row[vq * 8]);
                #pragma unroll
                for (int j = 0; j < 8; ++j)
                    acc += w_s[tap][vq * 8 + j] * (float)v[j];
            }
        }
    }
    ksp[pbase + p] = acc;
}

// ---------------------------------------------------------------------------
__global__ __launch_bounds__(256) void sp_kernel(
    const float* __restrict__ ksp, const float* __restrict__ w_sp,
    float* __restrict__ sp)
{
    const int p = blockIdx.x * 256 + threadIdx.x;
    const int n = blockIdx.y;
    const int h = p / 96, w = p % 96;
    const float* kp = ksp + (long)n * HW;
    float acc = 0.f;
    #pragma unroll
    for (int dy = 0; dy < 3; ++dy)
        #pragma unroll
        for (int dx = 0; dx < 3; ++dx) {
            int hh = h + dy - 1, ww = w + dx - 1;
            if (hh < 0 || hh >= 96 || ww < 0 || ww >= 96) continue;
            float s = 0.f, m = -1e30f;
            #pragma unroll
            for (int iy = 0; iy < 3; ++iy)
                #pragma unroll
                for (int ix = 0; ix < 3; ++ix) {
                    int h2 = hh + iy - 1, w2 = ww + ix - 1;
                    float v = (h2 >= 0 && h2 < 96 && w2 >= 0 && w2 < 96) ? kp[h2 * 96 + w2] : 0.f;
                    s += v; m = fmaxf(m, v);
                }
            acc += w_sp[dy * 3 + dx] * (s * (1.f / 9.f)) + w_sp[9 + dy * 3 + dx] * m;
        }
    sp[(long)n * HW + p] = 1.f / (1.f + expf(-acc));
}

// ---------------------------------------------------------------------------
// spatial_after -> catfb ch128..255 (raw-reshape gather; cc = p/72)
// xd holds ONLY x2 ([N][128][HW] fp32).
// ---------------------------------------------------------------------------
__global__ __launch_bounds__(256) void spatial_kernel(
    const float* __restrict__ xd, const float* __restrict__ ks,
    const float* __restrict__ sp, __hip_bfloat16* __restrict__ catfb)
{
    const int cc = blockIdx.x;
    const int n  = blockIdx.y;
    const int tid = threadIdx.x;
    __shared__ float plane[HW];
    const float* src = xd + ((long)n * 128 + cc) * HW;
    for (int i = tid; i < HW / 4; i += 256)
        *reinterpret_cast<float4*>(&plane[i * 4]) = *reinterpret_cast<const float4*>(&src[i * 4]);
    __syncthreads();
    const int c  = tid & 127;
    const int pr = tid >> 7;
    const int c9 = c * 9;
    for (int j = 0; j < 36; ++j) {
        const int pl = pr + j * 2;
        const int p  = cc * 72 + pl;
        float spv = sp[(long)n * HW + p];
        float kv[9];
        #pragma unroll
        for (int k = 0; k < 9; ++k) kv[k] = ks[((long)n * 9 + k) * HW + p] * spv;
        const int base = pl * 1152 + c9;
        int kk0 = base / 9216;
        int r20 = base - kk0 * 9216;
        int h20 = r20 / 96;
        int w20 = r20 - h20 * 96;
        float acc = 0.f;
        #pragma unroll
        for (int k = 0; k < 9; ++k) {
            int kk = kk0, h2 = h20, w2 = w20 + k;
            if (w2 >= 96) { h2 += 1; w2 -= 96; }
            if (h2 >= 96) { kk += 1; h2 -= 96; }
            int hh = h2 + kk / 3 - 1;
            int ww = w2 + kk % 3 - 1;
            float v = (hh >= 0 && hh < 96 && ww >= 0 && ww < 96) ? plane[hh * 96 + ww] : 0.f;
            acc += v * kv[k];
        }
        catfb[((long)n * HW + p) * 256 + 128 + c] = __float2bfloat16(acc);
    }
}

// ---------------------------------------------------------------------------
extern "C" void kernel_launch(void* const* d_in, const int* in_sizes, int n_in,
                              void* d_out, int out_size, void* d_ws, size_t ws_size,
                              hipStream_t stream)
{
    const float* x      = (const float*)d_in[0];
    const float* y      = (const float*)d_in[1];
    const float* w_down = (const float*)d_in[2];
    const float* b_down = (const float*)d_in[3];
    const float* w_ce   = (const float*)d_in[4];
    const float* w_gd   = (const float*)d_in[5];
    const float* bn_g   = (const float*)d_in[6];
    const float* bn_b   = (const float*)d_in[7];
    const float* w_kc   = (const float*)d_in[8];
    const float* b_kc   = (const float*)d_in[9];
    const float* w_ks1  = (const float*)d_in[10];
    const float* b_ks1  = (const float*)d_in[11];
    const float* w_ks2  = (const float*)d_in[12];
    const float* b_ks2  = (const float*)d_in[13];
    const float* w_sp1  = (const float*)d_in[14];
    const float* w_sp   = (const float*)d_in[15];
    const float* w_fb   = (const float*)d_in[16];
    const float* b_fb   = (const float*)d_in[17];
    const float* w_fuse = (const float*)d_in[18];
    const float* bn2_g  = (const float*)d_in[19];
    const float* bn2_b  = (const float*)d_in[20];
    const float* prelu  = (const float*)d_in[21];
    float* out = (float*)d_out;
    char* ws = (char*)d_ws;

    const long HWl = HW;
    // --- workspace layout ---
    float* xd = (float*)ws;                               ws += 8L * 128 * HWl * 4;  // 37.7MB (x2 only)
    char* region2 = ws;                                   ws += 8L * HWl * 512 * 2;  // 75.5MB
    __hip_bfloat16* x_t      = (__hip_bfloat16*)region2;          // [N][HW][512] bf16
    __hip_bfloat16* cat_r1   = (__hip_bfloat16*)region2;          // [N][HW][256] bf16
    __hip_bfloat16* ksmid_bf = (__hip_bfloat16*)region2;          // [N][HW][128] bf16
    __hip_bfloat16* catfb    = (__hip_bfloat16*)(region2 + 8L * HWl * 256 * 2); // [N][HW][256]
    __hip_bfloat16* cat_x  = (__hip_bfloat16*)ws;         ws += 8L * HWl * 256 * 2;  // 37.7MB
    __hip_bfloat16* y2t    = (__hip_bfloat16*)ws;         ws += 8L * HWl * 128 * 2;  // 18.9MB
    __hip_bfloat16* wdown_bf = (__hip_bfloat16*)ws;       ws += 1L * 256 * 512 * 2;
    __hip_bfloat16* wks1_bf  = (__hip_bfloat16*)ws;       ws += 9L * 128 * 128 * 2;
    __hip_bfloat16* wfb_bf   = (__hip_bfloat16*)ws;       ws += 9L * 256 * 256 * 2;
    __hip_bfloat16* wfuse_bf = (__hip_bfloat16*)ws;       ws += 9L * 256 * 512 * 2;
    float* ks   = (float*)ws;  ws += 8L * 9 * HWl * 4;
    float* ksp  = (float*)ws;  ws += 8L * HWl * 4;
    float* spb  = (float*)ws;  ws += 8L * HWl * 4;
    float* gl   = (float*)ws;  ws += 8L * 128 * 9 * 4;
    float* py   = (float*)ws;  ws += 8L * 128 * 9 * 4;
    float* kc   = (float*)ws;  ws += 8L * 128 * 9 * 4;
    __hip_bfloat16* zp = (__hip_bfloat16*)ws;  ws += 256;

    (void)hipMemsetAsync((void*)zp, 0, 256, stream);

    // all weight conversions in one launch
    wconv_all_kernel<<<dim3(512, 4), 256, 0, stream>>>(
        w_down, w_ks1, w_fb, w_fuse, wdown_bf, wks1_bf, wfb_bf, wfuse_bf);

    // x -> NHWC bf16, then 1x1 down conv -> xd (x2 only, fp32) + cat_x (bf16 NHWC)
    nchw2nhwc_kernel<<<dim3(144, 16, 8), 256, 0, stream>>>(x, 512L * HWl, x_t, 512);
    mfma_conv<512, 1, false, 3><<<dim3(768), 512, 102400, stream>>>(
        x_t, nullptr, wdown_bf, b_down, xd, 128L * HWl, 128, cat_x, 256, 256,
        nullptr, nullptr, nullptr, zp);

    // y2 -> NHWC bf16
    nchw2nhwc_kernel<<<dim3(144, 4, 8), 256, 0, stream>>>(y + 128L * HWl, 256L * HWl, y2t, 128);

    // pools / attention
    pool_x_nhwc_kernel<<<dim3(9, 8), 256, 0, stream>>>(cat_x, gl);
    pool_y_kernel<<<dim3(128, 8), 256, 0, stream>>>(y, py);
    attkc_kernel<<<dim3(8), 128, 0, stream>>>(gl, py, w_ce, w_gd, bn_g, bn_b, w_kc, b_kc, kc);

    // ks_mid = conv3x3(y2) -> ksmid_bf (bf16 NHWC; x_t dead now)
    mfma_conv<128, 9, false, 2><<<dim3(384), 512, 162304, stream>>>(
        y2t, nullptr, wks1_bf, b_ks1, nullptr, 0, 0, ksmid_bf, 128, 128,
        nullptr, nullptr, nullptr, zp);
    ks_nhwc_kernel<<<dim3(36, 8), 256, 0, stream>>>(ksmid_bf, w_ks2, b_ks2, ks);

    // ksp / sp  (ksp NHWC data-parallel from cat_x ch128..255)
    ksp_nhwc_kernel<<<dim3(36, 8), 256, 0, stream>>>(cat_x, w_sp1, ksp);
    sp_kernel<<<dim3(36, 8), 256, 0, stream>>>(ksp, w_sp, spb);

    // spatial_after -> catfb ch128..255 ; channel_after -> catfb ch0..127
    spatial_kernel<<<dim3(128, 8), 256, 0, stream>>>(xd, ks, spb, catfb);
    channel_nhwc_kernel<<<dim3(96, 8), 256, 0, stream>>>(cat_x, kc, catfb);

    // r1 = conv3x3(catfb, w_fb)+b -> cat_r1 (bf16 NHWC; ksmid dead)
    mfma_conv<256, 9, false, 3><<<dim3(768), 512, 162304, stream>>>(
        catfb, nullptr, wfb_bf, b_fb, nullptr, 0, 0, cat_r1, 256, 256,
        nullptr, nullptr, nullptr, zp);

    // out = prelu(bn(conv3x3([cat_x | cat_r1], w_fuse)))
    mfma_conv<512, 9, true, 3><<<dim3(768), 512, 162304, stream>>>(
        cat_x, cat_r1, wfuse_bf, nullptr, out, 256L * HWl, 0, nullptr, 0, 256,
        bn2_g, bn2_b, prelu, zp);
}

// Round 17
// 611.099 us; speedup vs baseline: 1.1548x; 1.0405x over previous
//
#include <hip/hip_runtime.h>
#include <hip/hip_bf16.h>
#include <math.h>

#define HW 9216
#define IMG 96

typedef __bf16 bf16x8 __attribute__((ext_vector_type(8)));
typedef float  f32x4  __attribute__((ext_vector_type(4)));

__device__ __forceinline__ void gload16(const void* g, void* l) {
    __builtin_amdgcn_global_load_lds((const unsigned int*)g, (unsigned int*)l, 16, 0, 0);
}

#define WAITVN(N) asm volatile("s_waitcnt vmcnt(" #N ")" ::: "memory")
#define BARX()    { asm volatile("" ::: "memory"); __builtin_amdgcn_s_barrier(); asm volatile("" ::: "memory"); }

// ---------------------------------------------------------------------------
// NCHW fp32 -> NHWC bf16 transpose/convert. grid (HW/64, cin/32, N)
// ---------------------------------------------------------------------------
__global__ __launch_bounds__(256) void nchw2nhwc_kernel(
    const float* __restrict__ src, long n_stride_src,
    __hip_bfloat16* __restrict__ dst, int dst_stride)
{
    __shared__ float tile[32][65];
    const int px0 = blockIdx.x * 64;
    const int c0  = blockIdx.y * 32;
    const int n   = blockIdx.z;
    const int tid = threadIdx.x;
    const int tx = tid & 63, ty = tid >> 6;
    #pragma unroll
    for (int i = 0; i < 8; ++i)
        tile[ty + i * 4][tx] = src[n * n_stride_src + (long)(c0 + ty + i * 4) * HW + px0 + tx];
    __syncthreads();
    const int ci = tid & 31, pxl = tid >> 5;
    #pragma unroll
    for (int j = 0; j < 8; ++j) {
        int px = pxl + j * 8;
        dst[((long)n * HW + px0 + px) * dst_stride + c0 + ci] = __float2bfloat16(tile[ci][px]);
    }
}

// ---------------------------------------------------------------------------
// all four weight conversions in ONE launch: dst[t][co][ci] = bf16(src[co][ci][t])
// ---------------------------------------------------------------------------
__global__ __launch_bounds__(256) void wconv_all_kernel(
    const float* __restrict__ w_down, const float* __restrict__ w_ks1,
    const float* __restrict__ w_fb,   const float* __restrict__ w_fuse,
    __hip_bfloat16* __restrict__ d_down, __hip_bfloat16* __restrict__ d_ks1,
    __hip_bfloat16* __restrict__ d_fb,   __hip_bfloat16* __restrict__ d_fuse)
{
    const float* src; __hip_bfloat16* dst; int cout, cin, taps;
    switch (blockIdx.y) {
        case 0:  src = w_down; dst = d_down; cout = 256; cin = 512; taps = 1; break;
        case 1:  src = w_ks1;  dst = d_ks1;  cout = 128; cin = 128; taps = 9; break;
        case 2:  src = w_fb;   dst = d_fb;   cout = 256; cin = 256; taps = 9; break;
        default: src = w_fuse; dst = d_fuse; cout = 256; cin = 512; taps = 9; break;
    }
    int idx = blockIdx.x * 256 + threadIdx.x;
    if (idx >= cout * cin) return;
    int co = idx / cin, ci = idx % cin;
    for (int t = 0; t < taps; ++t)
        dst[((long)t * cout + co) * cin + ci] = __float2bfloat16(src[(long)idx * taps + t]);
}

// ---------------------------------------------------------------------------
// MFMA implicit-GEMM conv (TAPS=9: 3x3 pad=1; TAPS=1: 1x1), bf16 in, fp32 acc.
// R10-proven geometry: 512 threads = 8 waves; tile co=32 x rows=8 x cols=96;
// ci-chunk 32; mfma 16x16x32. LDS 162,304 B -> 1 block/CU, 2 waves/SIMD.
// Counted per-wave vmcnt keeps next-chunk stage in flight across the barrier
// (counts are per-wave MINIMUM issued -> conservative, no under-wait).
// B-ADDRESS FOLDING (R17): qb = lg^((c>>1)&3) is invariant in nf (c += 16
// preserves (c>>1)&3) and nf-consecutive addresses differ by exactly 1024B,
// so per (g,kx) we compute ONE base and read bbase + nf*1024 (compile-time
// immediate) -> 9 address chains per chunk instead of 54 (~200 VALU saved).
// T1 XCD swizzle: y = (id>>3)&(NY-1); xz = (id&7) + 8*(id>>(3+NYL2)).
// NCHW output only for co >= nchw_co0. SPLIT: dAB = (B - A) - 448 at ch 7->8.
// ---------------------------------------------------------------------------
template<int CIN, int TAPS, bool SPLIT, int NYL2>
__global__ __launch_bounds__(512, 1) void mfma_conv(
    const __hip_bfloat16* __restrict__ in_a,
    const __hip_bfloat16* __restrict__ in_b,
    const __hip_bfloat16* __restrict__ w_t,
    const float* __restrict__ bias,
    float* __restrict__ out_nchw, long nchw_nstride, int nchw_co0,
    __hip_bfloat16* __restrict__ out_nhwc, int nhwc_stride,
    int cout,
    const float* __restrict__ bng, const float* __restrict__ bnb,
    const float* __restrict__ pra,
    const __hip_bfloat16* __restrict__ zeropage)
{
    constexpr int ROWS = (TAPS == 9) ? 10 : 8;      // staged rows
    constexpr int COLS = (TAPS == 9) ? 98 : 96;
    constexpr int HOFF = (TAPS == 9) ? 1 : 0;
    constexpr int PSTR = SPLIT ? 256 : CIN;
    constexpr int NSEG_IN = ROWS * COLS * 4;        // 3920 / 3072
    constexpr int NSEG_W  = TAPS * 32 * 4;          // 1152 / 128
    constexpr int IN_BYTES = NSEG_IN * 16;          // 62720 / 49152
    constexpr int BUF = IN_BYTES + NSEG_W * 16;     // 81152 / 51200
    constexpr int NCHUNK = CIN / 32;
    constexpr int FULL_IN = NSEG_IN / 512;          // 7 / 6
    constexpr int IN_TAIL = NSEG_IN % 512;          // 336 / 0
    constexpr int FULL_W  = NSEG_W / 512;           // 2 / 0
    constexpr int W_TAIL  = NSEG_W % 512;           // 128 / 128
    constexpr int IT_IN = FULL_IN + (IN_TAIL ? 1 : 0);
    constexpr int IT_W  = FULL_W + (W_TAIL ? 1 : 0);
    constexpr int GROUPS = (TAPS == 9) ? 3 : 1;
    constexpr int KXN    = (TAPS == 9) ? 3 : 1;

    extern __shared__ __align__(16) char lds[];     // 2*BUF

    // ---- XCD-aware decode of flat block id ----
    const int id  = blockIdx.x;
    const int yb  = (id >> 3) & ((1 << NYL2) - 1);
    const int xz  = (id & 7) + 8 * (id >> (3 + NYL2));
    const int h0  = (xz % 12) * 8;
    const int n   = xz / 12;
    const int cob = yb * 32;

    const int tid  = threadIdx.x;
    const int lane = tid & 63;
    const int wave = tid >> 6;
    const int l16  = lane & 15, lg = lane >> 4;

    const long dAB = SPLIT ? ((const char*)in_b - (const char*)in_a - 448) : 0;

    // ---- input staging pointers (advance 64B per ci-chunk) ----
    const char* inptr[IT_IN];
    int inval[IT_IN];
    #pragma unroll
    for (int t = 0; t < IT_IN; ++t) {
        int seg = tid + t * 512;
        int s2 = (seg < NSEG_IN) ? seg : 0;
        int pix = s2 >> 2, qp = s2 & 3;
        int r = pix / COLS, c = pix % COLS;
        int h = h0 + r - HOFF, w = c - HOFF;
        int q = qp ^ ((c >> 1) & 3);                 // inverse-swizzled source slot
        bool valid = (h >= 0 && h < IMG && w >= 0 && w < IMG);
        inptr[t] = valid
            ? (const char*)(in_a + ((long)n * HW + h * IMG + w) * PSTR + q * 8)
            : (const char*)zeropage;
        inval[t] = valid ? 1 : 0;
    }
    // ---- weight staging pointers ----
    const char* wptr[IT_W];
    #pragma unroll
    for (int t = 0; t < IT_W; ++t) {
        int seg = tid + t * 512;
        int s2 = (seg < NSEG_W) ? seg : 0;
        int tap = s2 >> 7, rem = s2 & 127;
        int co = rem >> 2, qp = rem & 3;
        int q = qp ^ ((co >> 1) & 3);
        wptr[t] = (const char*)(w_t + ((long)tap * cout + cob + co) * CIN + q * 8);
    }

    auto stage = [&](int bb, long adv) {
        char* ib = lds + bb * BUF;
        char* wb = ib + IN_BYTES;
        #pragma unroll
        for (int t = 0; t < FULL_IN; ++t) {
            gload16(inptr[t], ib + (tid + t * 512) * 16);
            if (inval[t]) inptr[t] += adv;
        }
        if (IN_TAIL) {
            if (tid < IN_TAIL) {
                gload16(inptr[IT_IN - 1], ib + (tid + FULL_IN * 512) * 16);
                if (inval[IT_IN - 1]) inptr[IT_IN - 1] += adv;
            }
        }
        #pragma unroll
        for (int t = 0; t < FULL_W; ++t) {
            gload16(wptr[t], wb + (tid + t * 512) * 16);
            wptr[t] += 64;
        }
        if (W_TAIL) {
            if (tid < W_TAIL) {
                gload16(wptr[IT_W - 1], wb + (tid + FULL_W * 512) * 16);
                wptr[IT_W - 1] += 64;
            }
        }
    };

    f32x4 acc[2][6];
    #pragma unroll
    for (int m = 0; m < 2; ++m)
        #pragma unroll
        for (int nf = 0; nf < 6; ++nf) acc[m][nf] = (f32x4){0.f, 0.f, 0.f, 0.f};

    const int qa = lg ^ ((l16 >> 1) & 3);
    const int a_off = l16 * 64 + qa * 16;

    stage(0, 64);
    WAITVN(0); BARX();

    for (int ch = 0; ch < NCHUNK; ++ch) {
        if (ch + 1 < NCHUNK) {
            long adv = (SPLIT && (ch + 1) == 7) ? dAB : 64;
            stage((ch + 1) & 1, adv);
            // per-wave MIN of loads just issued (conservative):
            // waves 0-1 (tid<128): 7+1 IN + 2+1 W = 11
            // waves 2-4 (tid 128-320): 8 IN + 2 W = 10
            // wave 5 (tid 320-384): mixed 10/9 -> wait 9
            // waves 6-7: 7 IN + 2 W = 9
            if constexpr (TAPS == 9) {
                if (wave < 2) { WAITVN(11); } else if (wave < 5) { WAITVN(10); } else { WAITVN(9); }
            } else {
                if (wave < 2) { WAITVN(7); } else { WAITVN(6); }
            }
        } else {
            WAITVN(0);
        }
        BARX();

        const char* ib = lds + (ch & 1) * BUF;
        const char* wb = ib + IN_BYTES;
        __builtin_amdgcn_s_setprio(1);
        #pragma unroll
        for (int g = 0; g < GROUPS; ++g) {
            const char* rowb = ib + (wave + g) * (COLS * 64);
            #pragma unroll
            for (int kx = 0; kx < KXN; ++kx) {
                const int tap = g * 3 + kx;          // compile-time in unroll
                bf16x8 a0 = *(const bf16x8*)(wb + tap * 2048 + a_off);
                bf16x8 a1 = *(const bf16x8*)(wb + tap * 2048 + 1024 + a_off);
                const int c0 = l16 + kx;
                const int qb = lg ^ ((c0 >> 1) & 3); // invariant in nf
                const char* bbase = rowb + c0 * 64 + qb * 16;
                #pragma unroll
                for (int nf = 0; nf < 6; ++nf) {
                    bf16x8 b = *(const bf16x8*)(bbase + nf * 1024);
                    acc[0][nf] = __builtin_amdgcn_mfma_f32_16x16x32_bf16(a0, b, acc[0][nf], 0, 0, 0);
                    acc[1][nf] = __builtin_amdgcn_mfma_f32_16x16x32_bf16(a1, b, acc[1][nf], 0, 0, 0);
                }
            }
        }
        __builtin_amdgcn_s_setprio(0);
        BARX();
    }

    // ---- epilogue ----
    const int hrow = h0 + wave;
    #pragma unroll
    for (int m = 0; m < 2; ++m) {
        const int co = cob + m * 16 + lg * 4;
        float bs[4], g4[4], b4[4], p4[4];
        #pragma unroll
        for (int r = 0; r < 4; ++r) bs[r] = bias ? bias[co + r] : 0.f;
        if (bng) {
            #pragma unroll
            for (int r = 0; r < 4; ++r) { g4[r] = bng[co + r]; b4[r] = bnb[co + r]; p4[r] = pra[co + r]; }
        }
        #pragma unroll
        for (int nf = 0; nf < 6; ++nf) {
            const int wcol = nf * 16 + l16;
            const long px = (long)hrow * IMG + wcol;
            float v[4];
            #pragma unroll
            for (int r = 0; r < 4; ++r) {
                v[r] = acc[m][nf][r] + bs[r];
                if (bng) {
                    v[r] = v[r] * g4[r] + b4[r];
                    v[r] = (v[r] >= 0.f) ? v[r] : p4[r] * v[r];
                }
            }
            if (out_nchw && co >= nchw_co0) {
                #pragma unroll
                for (int r = 0; r < 4; ++r)
                    out_nchw[(long)n * nchw_nstride + (long)(co - nchw_co0 + r) * HW + px] = v[r];
            }
            if (out_nhwc) {
                union { __hip_bfloat16 h[4]; uint2 u; } pk;
                #pragma unroll
                for (int r = 0; r < 4; ++r) pk.h[r] = __float2bfloat16(v[r]);
                *reinterpret_cast<uint2*>(&out_nhwc[((long)n * HW + px) * nhwc_stride + co]) = pk.u;
            }
        }
    }
}

// ---------------------------------------------------------------------------
// pool_to_3x3 for x1 from cat_x (bf16 NHWC ch0..127). grid (9 bins, N).
// ---------------------------------------------------------------------------
__global__ __launch_bounds__(256) void pool_x_nhwc_kernel(
    const __hip_bfloat16* __restrict__ catx, float* __restrict__ gl)
{
    const int bin = blockIdx.x;
    const int n   = blockIdx.y;
    const int bh = bin / 3, bw = bin % 3;
    const int tid = threadIdx.x;
    const int cg  = tid & 15;      // channel group (8 ch)
    const int pxl = tid >> 4;      // pixel lane (16)
    const long pbase = (long)n * HW;
    float acc[8];
    #pragma unroll
    for (int j = 0; j < 8; ++j) acc[j] = 0.f;
    for (int it = 0; it < 64; ++it) {
        const int i = pxl + it * 16;           // 0..1023
        const int h = bh * 32 + (i >> 5);
        const int w = bw * 32 + (i & 31);
        bf16x8 v = *reinterpret_cast<const bf16x8*>(&catx[(pbase + h * IMG + w) * 256 + cg * 8]);
        #pragma unroll
        for (int j = 0; j < 8; ++j) acc[j] += (float)v[j];
    }
    __shared__ float red[16][16][8];
    #pragma unroll
    for (int j = 0; j < 8; ++j) red[pxl][cg][j] = acc[j];
    __syncthreads();
    if (tid < 128) {
        const int cg2 = tid & 15, j = tid >> 4;
        float s = 0.f;
        #pragma unroll
        for (int p = 0; p < 16; ++p) s += red[p][cg2][j];
        gl[((long)n * 128 + cg2 * 8 + j) * 9 + bin] = s * (1.f / 1024.f);
    }
}

// ---------------------------------------------------------------------------
// pool_to_3x3 for y1 (y ch 0..127, fp32 NCHW). grid (128, N).
// ---------------------------------------------------------------------------
__global__ __launch_bounds__(256) void pool_y_kernel(
    const float* __restrict__ y, float* __restrict__ py)
{
    const int c = blockIdx.x, n = blockIdx.y;
    const int tid = threadIdx.x;
    const float* src = y + ((long)n * 256 + c) * HW;
    float local[9];
    #pragma unroll
    for (int k = 0; k < 9; ++k) local[k] = 0.f;
    for (int i = tid; i < HW; i += 256) {
        int h = i / 96, w = i % 96;
        local[(h / 32) * 3 + (w / 32)] += src[i];
    }
    __shared__ float red[9][4];
    const int wv = tid >> 6, lane = tid & 63;
    #pragma unroll
    for (int k = 0; k < 9; ++k) {
        float v = local[k];
        for (int off = 32; off > 0; off >>= 1) v += __shfl_down(v, off, 64);
        if (lane == 0) red[k][wv] = v;
    }
    __syncthreads();
    if (tid < 9) {
        float s = (red[tid][0] + red[tid][1] + red[tid][2] + red[tid][3]) * (1.f / 1024.f);
        py[((long)n * 128 + c) * 9 + tid] = s;
    }
}

// ---------------------------------------------------------------------------
__global__ __launch_bounds__(128) void attkc_kernel(
    const float* __restrict__ gl, const float* __restrict__ py,
    const float* __restrict__ w_ce, const float* __restrict__ w_gd,
    const float* __restrict__ bng, const float* __restrict__ bnb,
    const float* __restrict__ w_kc, const float* __restrict__ b_kc,
    float* __restrict__ kc)
{
    const int n = blockIdx.x, c = threadIdx.x;
    __shared__ float py_s[128][9];
    #pragma unroll
    for (int k = 0; k < 9; ++k) py_s[c][k] = py[((long)n * 128 + c) * 9 + k];
    __syncthreads();
    float g[9];
    #pragma unroll
    for (int k = 0; k < 9; ++k) g[k] = gl[((long)n * 128 + c) * 9 + k];
    float t[5];
    #pragma unroll
    for (int l = 0; l < 5; ++l) {
        float s = 0.f;
        #pragma unroll
        for (int k = 0; k < 9; ++k) s += g[k] * w_ce[l * 9 + k];
        s = s * bng[c] + bnb[c];
        t[l] = s > 0.f ? s : 0.f;
    }
    float att[9];
    #pragma unroll
    for (int k = 0; k < 9; ++k) {
        float s = 0.f;
        #pragma unroll
        for (int l = 0; l < 5; ++l) s += t[l] * w_gd[k * 5 + l];
        att[k] = 1.f / (1.f + expf(-s));
    }
    float kc0[9];
    float bk = b_kc[c];
    #pragma unroll
    for (int k = 0; k < 9; ++k) kc0[k] = bk;
    for (int c2 = 0; c2 < 128; ++c2) {
        float wv = w_kc[c * 128 + c2];
        #pragma unroll
        for (int k = 0; k < 9; ++k) kc0[k] += wv * py_s[c2][k];
    }
    #pragma unroll
    for (int k = 0; k < 9; ++k)
        kc[((long)n * 128 + c) * 9 + k] = kc0[k] * att[k];
}

// ---------------------------------------------------------------------------
// channel_after, NHWC form: reads cat_x (bf16 NHWC ch0..127 = x1), kc in regs,
// writes catfb ch0..127 (bf16 NHWC). Block = one row h; thread: 8 ch x 16 px.
// ---------------------------------------------------------------------------
__global__ __launch_bounds__(256) void channel_nhwc_kernel(
    const __hip_bfloat16* __restrict__ catx, const float* __restrict__ kc,
    __hip_bfloat16* __restrict__ catfb)
{
    const int h  = blockIdx.x;
    const int n  = blockIdx.y;
    const int cg = (threadIdx.x & 15) * 8;
    const int w0 = threadIdx.x >> 4;
    float k9[8][9];
    #pragma unroll
    for (int j = 0; j < 8; ++j)
        #pragma unroll
        for (int t = 0; t < 9; ++t) k9[j][t] = kc[((long)n * 128 + cg + j) * 9 + t];
    const long pbase = (long)n * HW;
    for (int it = 0; it < 6; ++it) {
        const int w = w0 + it * 16;
        float acc[8];
        #pragma unroll
        for (int j = 0; j < 8; ++j) acc[j] = 0.f;
        #pragma unroll
        for (int ky = 0; ky < 3; ++ky) {
            const int hh = h + ky - 1;
            if (hh < 0 || hh >= IMG) continue;
            #pragma unroll
            for (int kx = 0; kx < 3; ++kx) {
                const int ww = w + kx - 1;
                if (ww < 0 || ww >= IMG) continue;
                bf16x8 v = *reinterpret_cast<const bf16x8*>(
                    &catx[(pbase + hh * IMG + ww) * 256 + cg]);
                #pragma unroll
                for (int j = 0; j < 8; ++j)
                    acc[j] += k9[j][ky * 3 + kx] * (float)v[j];
            }
        }
        union { __hip_bfloat16 hh[8]; uint4 u; } pk;
        #pragma unroll
        for (int j = 0; j < 8; ++j) pk.hh[j] = __float2bfloat16(acc[j]);
        *reinterpret_cast<uint4*>(&catfb[(pbase + h * IMG + w) * 256 + cg]) = pk.u;
    }
}

// ---------------------------------------------------------------------------
// ks = 1x1 conv 128->9 on ksmid_bf [N][HW][128] bf16 (NHWC)
// ---------------------------------------------------------------------------
__global__ __launch_bounds__(256) void ks_nhwc_kernel(
    const __hip_bfloat16* __restrict__ ksmid, const float* __restrict__ w_ks2,
    const float* __restrict__ b_ks2, float* __restrict__ ks)
{
    __shared__ float w_s[9 * 128];
    const int tid = threadIdx.x;
    for (int i = tid; i < 1152; i += 256) w_s[i] = w_ks2[i];
    __syncthreads();
    const int p = blockIdx.x * 256 + tid;
    const int n = blockIdx.y;
    const __hip_bfloat16* row = ksmid + ((long)n * HW + p) * 128;
    float acc[9];
    #pragma unroll
    for (int k = 0; k < 9; ++k) acc[k] = b_ks2[k];
    #pragma unroll
    for (int vq = 0; vq < 16; ++vq) {
        bf16x8 v = *reinterpret_cast<const bf16x8*>(&row[vq * 8]);
        #pragma unroll
        for (int j = 0; j < 8; ++j) {
            float f = (float)v[j];
            #pragma unroll
            for (int k = 0; k < 9; ++k) acc[k] += w_s[k * 128 + vq * 8 + j] * f;
        }
    }
    #pragma unroll
    for (int k = 0; k < 9; ++k) ks[((long)n * 9 + k) * HW + p] = acc[k];
}

// ---------------------------------------------------------------------------
// ksp = conv3x3(x2, w_sp1, pad=1) -> 1 channel, NHWC data-parallel.
// ---------------------------------------------------------------------------
__global__ __launch_bounds__(256) void ksp_nhwc_kernel(
    const __hip_bfloat16* __restrict__ catx, const float* __restrict__ w_sp1,
    float* __restrict__ ksp)
{
    __shared__ float w_s[9][128];
    const int tid = threadIdx.x;
    for (int i = tid; i < 1152; i += 256) {
        int ci = i / 9, tap = i % 9;            // src layout [ci][tap]
        w_s[tap][ci] = w_sp1[i];
    }
    __syncthreads();
    const int p = blockIdx.x * 256 + tid;
    const int n = blockIdx.y;
    const int h = p / 96, w = p % 96;
    const long pbase = (long)n * HW;
    float acc = 0.f;
    #pragma unroll
    for (int ky = 0; ky < 3; ++ky) {
        const int hh = h + ky - 1;
        if (hh < 0 || hh >= IMG) continue;
        #pragma unroll
        for (int kx = 0; kx < 3; ++kx) {
            const int ww = w + kx - 1;
            if (ww < 0 || ww >= IMG) continue;
            const int tap = ky * 3 + kx;
            const __hip_bfloat16* row = &catx[(pbase + hh * IMG + ww) * 256 + 128];
            #pragma unroll
            for (int vq = 0; vq < 16; ++vq) {
                bf16x8 v = *reinterpret_cast<const bf16x8*>(&row[vq * 8]);
                #pragma unroll
                for (int j = 0; j < 8; ++j)
                    acc += w_s[tap][vq * 8 + j] * (float)v[j];
            }
        }
    }
    ksp[pbase + p] = acc;
}

// ---------------------------------------------------------------------------
__global__ __launch_bounds__(256) void sp_kernel(
    const float* __restrict__ ksp, const float* __restrict__ w_sp,
    float* __restrict__ sp)
{
    const int p = blockIdx.x * 256 + threadIdx.x;
    const int n = blockIdx.y;
    const int h = p / 96, w = p % 96;
    const float* kp = ksp + (long)n * HW;
    float acc = 0.f;
    #pragma unroll
    for (int dy = 0; dy < 3; ++dy)
        #pragma unroll
        for (int dx = 0; dx < 3; ++dx) {
            int hh = h + dy - 1, ww = w + dx - 1;
            if (hh < 0 || hh >= 96 || ww < 0 || ww >= 96) continue;
            float s = 0.f, m = -1e30f;
            #pragma unroll
            for (int iy = 0; iy < 3; ++iy)
                #pragma unroll
                for (int ix = 0; ix < 3; ++ix) {
                    int h2 = hh + iy - 1, w2 = ww + ix - 1;
                    float v = (h2 >= 0 && h2 < 96 && w2 >= 0 && w2 < 96) ? kp[h2 * 96 + w2] : 0.f;
                    s += v; m = fmaxf(m, v);
                }
            acc += w_sp[dy * 3 + dx] * (s * (1.f / 9.f)) + w_sp[9 + dy * 3 + dx] * m;
        }
    sp[(long)n * HW + p] = 1.f / (1.f + expf(-acc));
}

// ---------------------------------------------------------------------------
// spatial_after -> catfb ch128..255 (raw-reshape gather; cc = p/72)
// xd holds ONLY x2 ([N][128][HW] fp32).
// ---------------------------------------------------------------------------
__global__ __launch_bounds__(256) void spatial_kernel(
    const float* __restrict__ xd, const float* __restrict__ ks,
    const float* __restrict__ sp, __hip_bfloat16* __restrict__ catfb)
{
    const int cc = blockIdx.x;
    const int n  = blockIdx.y;
    const int tid = threadIdx.x;
    __shared__ float plane[HW];
    const float* src = xd + ((long)n * 128 + cc) * HW;
    for (int i = tid; i < HW / 4; i += 256)
        *reinterpret_cast<float4*>(&plane[i * 4]) = *reinterpret_cast<const float4*>(&src[i * 4]);
    __syncthreads();
    const int c  = tid & 127;
    const int pr = tid >> 7;
    const int c9 = c * 9;
    for (int j = 0; j < 36; ++j) {
        const int pl = pr + j * 2;
        const int p  = cc * 72 + pl;
        float spv = sp[(long)n * HW + p];
        float kv[9];
        #pragma unroll
        for (int k = 0; k < 9; ++k) kv[k] = ks[((long)n * 9 + k) * HW + p] * spv;
        const int base = pl * 1152 + c9;
        int kk0 = base / 9216;
        int r20 = base - kk0 * 9216;
        int h20 = r20 / 96;
        int w20 = r20 - h20 * 96;
        float acc = 0.f;
        #pragma unroll
        for (int k = 0; k < 9; ++k) {
            int kk = kk0, h2 = h20, w2 = w20 + k;
            if (w2 >= 96) { h2 += 1; w2 -= 96; }
            if (h2 >= 96) { kk += 1; h2 -= 96; }
            int hh = h2 + kk / 3 - 1;
            int ww = w2 + kk % 3 - 1;
            float v = (hh >= 0 && hh < 96 && ww >= 0 && ww < 96) ? plane[hh * 96 + ww] : 0.f;
            acc += v * kv[k];
        }
        catfb[((long)n * HW + p) * 256 + 128 + c] = __float2bfloat16(acc);
    }
}

// ---------------------------------------------------------------------------
extern "C" void kernel_launch(void* const* d_in, const int* in_sizes, int n_in,
                              void* d_out, int out_size, void* d_ws, size_t ws_size,
                              hipStream_t stream)
{
    const float* x      = (const float*)d_in[0];
    const float* y      = (const float*)d_in[1];
    const float* w_down = (const float*)d_in[2];
    const float* b_down = (const float*)d_in[3];
    const float* w_ce   = (const float*)d_in[4];
    const float* w_gd   = (const float*)d_in[5];
    const float* bn_g   = (const float*)d_in[6];
    const float* bn_b   = (const float*)d_in[7];
    const float* w_kc   = (const float*)d_in[8];
    const float* b_kc   = (const float*)d_in[9];
    const float* w_ks1  = (const float*)d_in[10];
    const float* b_ks1  = (const float*)d_in[11];
    const float* w_ks2  = (const float*)d_in[12];
    const float* b_ks2  = (const float*)d_in[13];
    const float* w_sp1  = (const float*)d_in[14];
    const float* w_sp   = (const float*)d_in[15];
    const float* w_fb   = (const float*)d_in[16];
    const float* b_fb   = (const float*)d_in[17];
    const float* w_fuse = (const float*)d_in[18];
    const float* bn2_g  = (const float*)d_in[19];
    const float* bn2_b  = (const float*)d_in[20];
    const float* prelu  = (const float*)d_in[21];
    float* out = (float*)d_out;
    char* ws = (char*)d_ws;

    const long HWl = HW;
    // --- workspace layout ---
    float* xd = (float*)ws;                               ws += 8L * 128 * HWl * 4;  // 37.7MB (x2 only)
    char* region2 = ws;                                   ws += 8L * HWl * 512 * 2;  // 75.5MB
    __hip_bfloat16* x_t      = (__hip_bfloat16*)region2;          // [N][HW][512] bf16
    __hip_bfloat16* cat_r1   = (__hip_bfloat16*)region2;          // [N][HW][256] bf16
    __hip_bfloat16* ksmid_bf = (__hip_bfloat16*)region2;          // [N][HW][128] bf16
    __hip_bfloat16* catfb    = (__hip_bfloat16*)(region2 + 8L * HWl * 256 * 2); // [N][HW][256]
    __hip_bfloat16* cat_x  = (__hip_bfloat16*)ws;         ws += 8L * HWl * 256 * 2;  // 37.7MB
    __hip_bfloat16* y2t    = (__hip_bfloat16*)ws;         ws += 8L * HWl * 128 * 2;  // 18.9MB
    __hip_bfloat16* wdown_bf = (__hip_bfloat16*)ws;       ws += 1L * 256 * 512 * 2;
    __hip_bfloat16* wks1_bf  = (__hip_bfloat16*)ws;       ws += 9L * 128 * 128 * 2;
    __hip_bfloat16* wfb_bf   = (__hip_bfloat16*)ws;       ws += 9L * 256 * 256 * 2;
    __hip_bfloat16* wfuse_bf = (__hip_bfloat16*)ws;       ws += 9L * 256 * 512 * 2;
    float* ks   = (float*)ws;  ws += 8L * 9 * HWl * 4;
    float* ksp  = (float*)ws;  ws += 8L * HWl * 4;
    float* spb  = (float*)ws;  ws += 8L * HWl * 4;
    float* gl   = (float*)ws;  ws += 8L * 128 * 9 * 4;
    float* py   = (float*)ws;  ws += 8L * 128 * 9 * 4;
    float* kc   = (float*)ws;  ws += 8L * 128 * 9 * 4;
    __hip_bfloat16* zp = (__hip_bfloat16*)ws;  ws += 256;

    (void)hipMemsetAsync((void*)zp, 0, 256, stream);

    // all weight conversions in one launch
    wconv_all_kernel<<<dim3(512, 4), 256, 0, stream>>>(
        w_down, w_ks1, w_fb, w_fuse, wdown_bf, wks1_bf, wfb_bf, wfuse_bf);

    // x -> NHWC bf16, then 1x1 down conv -> xd (x2 only, fp32) + cat_x (bf16 NHWC)
    nchw2nhwc_kernel<<<dim3(144, 16, 8), 256, 0, stream>>>(x, 512L * HWl, x_t, 512);
    mfma_conv<512, 1, false, 3><<<dim3(768), 512, 102400, stream>>>(
        x_t, nullptr, wdown_bf, b_down, xd, 128L * HWl, 128, cat_x, 256, 256,
        nullptr, nullptr, nullptr, zp);

    // y2 -> NHWC bf16
    nchw2nhwc_kernel<<<dim3(144, 4, 8), 256, 0, stream>>>(y + 128L * HWl, 256L * HWl, y2t, 128);

    // pools / attention
    pool_x_nhwc_kernel<<<dim3(9, 8), 256, 0, stream>>>(cat_x, gl);
    pool_y_kernel<<<dim3(128, 8), 256, 0, stream>>>(y, py);
    attkc_kernel<<<dim3(8), 128, 0, stream>>>(gl, py, w_ce, w_gd, bn_g, bn_b, w_kc, b_kc, kc);

    // ks_mid = conv3x3(y2) -> ksmid_bf (bf16 NHWC; x_t dead now)
    mfma_conv<128, 9, false, 2><<<dim3(384), 512, 162304, stream>>>(
        y2t, nullptr, wks1_bf, b_ks1, nullptr, 0, 0, ksmid_bf, 128, 128,
        nullptr, nullptr, nullptr, zp);
    ks_nhwc_kernel<<<dim3(36, 8), 256, 0, stream>>>(ksmid_bf, w_ks2, b_ks2, ks);

    // ksp / sp  (ksp NHWC data-parallel from cat_x ch128..255)
    ksp_nhwc_kernel<<<dim3(36, 8), 256, 0, stream>>>(cat_x, w_sp1, ksp);
    sp_kernel<<<dim3(36, 8), 256, 0, stream>>>(ksp, w_sp, spb);

    // spatial_after -> catfb ch128..255 ; channel_after -> catfb ch0..127
    spatial_kernel<<<dim3(128, 8), 256, 0, stream>>>(xd, ks, spb, catfb);
    channel_nhwc_kernel<<<dim3(96, 8), 256, 0, stream>>>(cat_x, kc, catfb);

    // r1 = conv3x3(catfb, w_fb)+b -> cat_r1 (bf16 NHWC; ksmid dead)
    mfma_conv<256, 9, false, 3><<<dim3(768), 512, 162304, stream>>>(
        catfb, nullptr, wfb_bf, b_fb, nullptr, 0, 0, cat_r1, 256, 256,
        nullptr, nullptr, nullptr, zp);

    // out = prelu(bn(conv3x3([cat_x | cat_r1], w_fuse)))
    mfma_conv<512, 9, true, 3><<<dim3(768), 512, 162304, stream>>>(
        cat_x, cat_r1, wfuse_bf, nullptr, out, 256L * HWl, 0, nullptr, 0, 256,
        bn2_g, bn2_b, prelu, zp);
}